// Round 2
// baseline (1664.869 us; speedup 1.0000x reference)
//
#include <hip/hip_runtime.h>
#include <math.h>

#define SDIM 1000
#define KPAD 1024
#define HDIM 200
#define MDIM 100
#define NPAD 208
#define TSTEPS 1024
#define BATCH 128
#define MT (BATCH*TSTEPS)
#define TOTX ((size_t)MT*(size_t)SDIM)

// ws layout: [0, 425984) WpT bf16 [208][1024]; [458752, +52428800) Z bf16 [131072][200]
#define Z_OFF 458752

typedef _Float16 half2_t __attribute__((ext_vector_type(2)));
typedef __attribute__((ext_vector_type(8))) short short8;
typedef __attribute__((ext_vector_type(4))) float f32x4;

static __device__ __forceinline__ unsigned short f2bf(float f) {
    unsigned u = __float_as_uint(f);
    unsigned r = 0x7fffu + ((u >> 16) & 1u);   // RNE
    return (unsigned short)((u + r) >> 16);
}
static __device__ __forceinline__ float bf2f(unsigned short h) {
    return __uint_as_float((unsigned)h << 16);
}
static __device__ __forceinline__ half2_t as_h2(unsigned v) {
    union { unsigned u; half2_t h; } c; c.u = v; return c.h;
}
static __device__ __forceinline__ unsigned as_u32(half2_t h) {
    union { half2_t h; unsigned u; } c; c.h = h; return c.u;
}
static __device__ __forceinline__ half2_t pk2(float a, float b) {
    half2_t r; r[0] = (_Float16)a; r[1] = (_Float16)b; return r;
}

// ---------------------------------------------------------------------------
// Kernel 0: WpT[n][k] = relu(w_s[k]) * W1[k][n]  (bf16, transposed, zero-padded
// to [208][1024]) so GEMM B-fragments are contiguous 16B per lane.
// ---------------------------------------------------------------------------
__global__ __launch_bounds__(256) void prep_wpt(const float* __restrict__ w_s,
                                                const float* __restrict__ W1,
                                                unsigned short* __restrict__ wpt) {
    int idx = blockIdx.x * 256 + threadIdx.x;   // 208*1024 total
    int n = idx >> 10, k = idx & (KPAD - 1);
    float v = 0.f;
    if (n < HDIM && k < SDIM) {
        float ws = fmaxf(w_s[k], 0.f);
        v = ws * W1[k * HDIM + n];
    }
    wpt[idx] = f2bf(v);
}

// ---------------------------------------------------------------------------
// Kernel 1: Z[m][n] = sum_k bf16(X[m][k]) * WpT[n][k], m = b*1024+t flat.
// 64-row blocks, 4 waves (one 16-row MFMA tile each), N = 13x16 = 208 (write 200).
// A staged fp32->bf16 in LDS (double-buffered); B fragments straight from L2.
// ---------------------------------------------------------------------------
__global__ __launch_bounds__(256) void gemm_z(const float* __restrict__ X,
                                              const unsigned short* __restrict__ wpt,
                                              unsigned short* __restrict__ Z) {
    __shared__ __align__(16) unsigned short Abuf[2][64][40];  // stride 40 breaks pow2 banks
    const int t = threadIdx.x;
    const int m0 = blockIdx.x * 64;
    const int srow = t >> 2, sseg = t & 3;
    const int lane = t & 63, w = t >> 6;

    f32x4 acc[13];
#pragma unroll
    for (int i = 0; i < 13; ++i) acc[i] = (f32x4){0.f, 0.f, 0.f, 0.f};

    auto stage = [&](int bsel, int k0) {
        size_t g = (size_t)(m0 + srow) * SDIM + (size_t)(k0 + sseg * 8);
        float v0=0.f,v1=0.f,v2=0.f,v3=0.f,v4=0.f,v5=0.f,v6=0.f,v7=0.f;
        if (g + 7 < TOTX) {          // k>=1000 reads next row: finite garbage * zero weight = 0
            float4 a = *(const float4*)(X + g);
            float4 b = *(const float4*)(X + g + 4);
            v0=a.x; v1=a.y; v2=a.z; v3=a.w; v4=b.x; v5=b.y; v6=b.z; v7=b.w;
        }
        short8 pk;
        pk[0]=(short)f2bf(v0); pk[1]=(short)f2bf(v1); pk[2]=(short)f2bf(v2); pk[3]=(short)f2bf(v3);
        pk[4]=(short)f2bf(v4); pk[5]=(short)f2bf(v5); pk[6]=(short)f2bf(v6); pk[7]=(short)f2bf(v7);
        *(short8*)&Abuf[bsel][srow][sseg * 8] = pk;
    };

    stage(0, 0);
#pragma unroll 1
    for (int it = 0; it < 32; ++it) {
        __syncthreads();
        if (it + 1 < 32) stage((it + 1) & 1, (it + 1) * 32);
        const int k0 = it * 32;
        const short8 av = *(const short8*)&Abuf[it & 1][w * 16 + (lane & 15)][(lane >> 4) * 8];
#pragma unroll
        for (int nt = 0; nt < 13; ++nt) {
            const short8 bv = *(const short8*)(wpt + (size_t)(nt * 16 + (lane & 15)) * KPAD
                                               + k0 + (lane >> 4) * 8);
            acc[nt] = __builtin_amdgcn_mfma_f32_16x16x32_bf16(av, bv, acc[nt], 0, 0, 0);
        }
    }

    // C/D layout: col = lane&15, row = (lane>>4)*4 + r
    const int colb = lane & 15;
    const int rowb = m0 + w * 16 + (lane >> 4) * 4;
#pragma unroll
    for (int nt = 0; nt < 13; ++nt) {
        int col = nt * 16 + colb;
        if (col < HDIM) {
#pragma unroll
            for (int r = 0; r < 4; ++r)
                Z[(size_t)(rowb + r) * HDIM + col] = f2bf(acc[nt][r]);
        }
    }
}

// ---------------------------------------------------------------------------
// Kernel 2: sequential scan. One WG (256 thr) per batch element.
//  u_t = ks*u_{t-1} + z_t            (thread n<200 owns u[n] in a register)
//  h   = relu(u + km@W1b + b1)       (mm1: thread n, 52 fdot2, W1b fp16 in regs)
//  a2  = h@W2                        (mm2: thread pair (n2, kc), k split 104/104)
//  m   = km + 3(1-km_kap)*1.7159*tanh(2/3*(a2+b2))   (even lanes own m[n2])
//  y   = m @ Wy + by                 (threads<80: (o,ks) 8-way k-split + shfl)
// 2 barriers per step; km for step t+1 packed at end of P3.
// ---------------------------------------------------------------------------
__global__ __launch_bounds__(256) void scan_seq(const unsigned short* __restrict__ Z,
        const float* __restrict__ W1, const float* __restrict__ b1,
        const float* __restrict__ W2, const float* __restrict__ b2,
        const float* __restrict__ Wy, const float* __restrict__ by,
        float* __restrict__ out) {
    __shared__ uint4 km_pk4[13];   // 52 half2: km pairs (k 0..99), [50..51]=0
    __shared__ uint4 h_pk4[26];    // 104 half2: h pairs (k 0..199), [100..103]=0
    __shared__ float m_lds[104];   // m[0..99], [100..103]=0

    const int t = threadIdx.x;
    const int b = blockIdx.x;
    const int n1 = t;              // mm1 output
    const int n2 = t >> 1, kc = t & 1;  // mm2 output / k-half
    const int o = t >> 3, ks = t & 7;   // y output / k-slice

    if (t < 104) m_lds[t] = 0.f;
    if (t < 13) km_pk4[t] = make_uint4(0, 0, 0, 0);
    if (t < 26) h_pk4[t] = make_uint4(0, 0, 0, 0);

    float b1r = (t < HDIM) ? b1[n1] : 0.f;

    half2_t w1r[52];               // W1b column n1, packed (k, k+1)
#pragma unroll
    for (int c = 0; c < 52; ++c) {
        float a0 = 0.f, a1 = 0.f;
        if (t < HDIM && c < 50) {
            a0 = W1[(SDIM + 2 * c) * HDIM + n1];
            a1 = W1[(SDIM + 2 * c + 1) * HDIM + n1];
        }
        w1r[c] = pk2(a0, a1);
    }

    half2_t w2r[52];               // W2 column n2, k-half kc (k = kc*104 + 2c, +1)
#pragma unroll
    for (int c = 0; c < 52; ++c) {
        float a0 = 0.f, a1 = 0.f;
        int k0i = kc * 104 + 2 * c;
        if (t < HDIM) {
            if (k0i < HDIM) a0 = W2[k0i * MDIM + n2];
            if (k0i + 1 < HDIM) a1 = W2[(k0i + 1) * MDIM + n2];
        }
        w2r[c] = pk2(a0, a1);
    }

    float kapr = 0.f, cmr = 0.f, b2r = 0.f;
    if (t < HDIM && kc == 0) {     // even lanes own m[n2]; kappa_m in fp64 to match numpy
        double lg = 1.0000000434294482
                  + (double)n2 * ((2.9999999995657055 - 1.0000000434294482) / 99.0);
        double tau = exp(lg * 2.302585092994046);
        kapr = (float)exp(-1.0 / tau);
        cmr = 3.0f * (1.0f - kapr);
        b2r = b2[n2];
    }

    float wyr[13];
    float byr = 0.f;
#pragma unroll
    for (int i = 0; i < 13; ++i) {
        int k = ks * 13 + i;
        wyr[i] = (t < 80 && k < MDIM) ? Wy[k * 10 + o] : 0.f;
    }
    if (t < 80) byr = by[o];

    const unsigned short* Zb = Z + (size_t)b * TSTEPS * HDIM;
    float* outb = out + (size_t)b * TSTEPS * 10;

    float u = 0.f;
    float m_kmn = 0.f;             // km for the *current* step (kappa_m * m_{t-1})
    unsigned short zreg = (t < HDIM) ? Zb[n1] : (unsigned short)0;

    __syncthreads();

#pragma unroll 1
    for (int st = 0; st < TSTEPS; ++st) {
        // ---- P2: mm1 -> h ----
        float h = 0.f;
        if (t < HDIM) {
            u = 0.81873075307798182f * u + bf2f(zreg);   // exp(-1/5)
            float acc = u + b1r;
#pragma unroll
            for (int c = 0; c < 13; ++c) {
                uint4 kp = km_pk4[c];
                acc = __builtin_amdgcn_fdot2(w1r[4*c+0], as_h2(kp.x), acc, false);
                acc = __builtin_amdgcn_fdot2(w1r[4*c+1], as_h2(kp.y), acc, false);
                acc = __builtin_amdgcn_fdot2(w1r[4*c+2], as_h2(kp.z), acc, false);
                acc = __builtin_amdgcn_fdot2(w1r[4*c+3], as_h2(kp.w), acc, false);
            }
            h = fmaxf(acc, 0.f);
            int stn = (st + 1 < TSTEPS) ? st + 1 : st;   // prefetch next z
            zreg = Zb[(size_t)stn * HDIM + n1];
        }
        float ho = __shfl_xor(h, 1);
        if (t < HDIM && kc == 0)
            ((unsigned*)h_pk4)[n2] = as_u32(pk2(h, ho));
        __syncthreads();

        // ---- P3: mm2 -> tanh -> m update; pack km for next step ----
        if (t < HDIM) {
            float a2 = 0.f;
#pragma unroll
            for (int c = 0; c < 13; ++c) {
                uint4 hp = h_pk4[kc * 13 + c];
                a2 = __builtin_amdgcn_fdot2(w2r[4*c+0], as_h2(hp.x), a2, false);
                a2 = __builtin_amdgcn_fdot2(w2r[4*c+1], as_h2(hp.y), a2, false);
                a2 = __builtin_amdgcn_fdot2(w2r[4*c+2], as_h2(hp.z), a2, false);
                a2 = __builtin_amdgcn_fdot2(w2r[4*c+3], as_h2(hp.w), a2, false);
            }
            a2 += __shfl_xor(a2, 1);
            if (kc == 0) {
                float x = (a2 + b2r) * (2.f / 3.f);
                float e = __expf(2.f * x);               // tanh(x) = 1 - 2/(e^{2x}+1)
                float dm = 1.7159f * (1.f - 2.f / (e + 1.f));
                float mnew = m_kmn + cmr * dm;
                m_lds[n2] = mnew;
                m_kmn = kapr * mnew;                     // km for step st+1
            }
        }
        {
            float kmo = __shfl_xor(m_kmn, 2);            // lane 4i gets km[2i+1] from 4i+2
            if (t < HDIM && (t & 3) == 0)
                ((unsigned*)km_pk4)[t >> 2] = as_u32(pk2(m_kmn, kmo));
        }
        __syncthreads();

        // ---- P4: y = m @ Wy + by ----
        if (t < 80) {
            float p = 0.f;
#pragma unroll
            for (int i = 0; i < 13; ++i) p += wyr[i] * m_lds[ks * 13 + i];
            p += __shfl_xor(p, 1);
            p += __shfl_xor(p, 2);
            p += __shfl_xor(p, 4);
            if (ks == 0) outb[st * 10 + o] = p + byr;
        }
    }
}

extern "C" void kernel_launch(void* const* d_in, const int* in_sizes, int n_in,
                              void* d_out, int out_size, void* d_ws, size_t ws_size,
                              hipStream_t stream) {
    const float* X  = (const float*)d_in[0];
    const float* ws = (const float*)d_in[1];
    const float* W1 = (const float*)d_in[2];
    const float* b1 = (const float*)d_in[3];
    const float* W2 = (const float*)d_in[4];
    const float* b2 = (const float*)d_in[5];
    const float* Wy = (const float*)d_in[6];
    const float* by = (const float*)d_in[7];
    float* out = (float*)d_out;

    unsigned short* wpt = (unsigned short*)d_ws;
    unsigned short* Z   = (unsigned short*)((char*)d_ws + Z_OFF);

    hipLaunchKernelGGL(prep_wpt, dim3((NPAD * KPAD) / 256), dim3(256), 0, stream, ws, W1, wpt);
    hipLaunchKernelGGL(gemm_z, dim3(MT / 64), dim3(256), 0, stream, X, wpt, Z);
    hipLaunchKernelGGL(scan_seq, dim3(BATCH), dim3(256), 0, stream,
                       Z, W1, b1, W2, b2, Wy, by, out);
}

// Round 3
// 1403.812 us; speedup vs baseline: 1.1860x; 1.1860x over previous
//
#include <hip/hip_runtime.h>
#include <math.h>

#define SDIM 1000
#define KPAD 1024
#define HDIM 200
#define MDIM 100
#define NPAD 208
#define TSTEPS 1024
#define BATCH 128
#define MT (BATCH*TSTEPS)
#define TOTX ((size_t)MT*(size_t)SDIM)

// ws layout: [0, 425984) WpT bf16 [208][1024]; [458752, +52428800) Z bf16 [131072][200]
#define Z_OFF 458752

typedef _Float16 half2_t __attribute__((ext_vector_type(2)));
typedef __attribute__((ext_vector_type(8))) short short8;
typedef __attribute__((ext_vector_type(4))) float f32x4;

static __device__ __forceinline__ unsigned short f2bf(float f) {
    unsigned u = __float_as_uint(f);
    unsigned r = 0x7fffu + ((u >> 16) & 1u);   // RNE
    return (unsigned short)((u + r) >> 16);
}
static __device__ __forceinline__ float bf2f(unsigned short h) {
    return __uint_as_float((unsigned)h << 16);
}
static __device__ __forceinline__ half2_t as_h2(unsigned v) {
    union { unsigned u; half2_t h; } c; c.u = v; return c.h;
}
static __device__ __forceinline__ unsigned as_u32(half2_t h) {
    union { half2_t h; unsigned u; } c; c.h = h; return c.u;
}
static __device__ __forceinline__ half2_t pk2(float a, float b) {
    half2_t r; r[0] = (_Float16)a; r[1] = (_Float16)b; return r;
}

// ---------------------------------------------------------------------------
// Kernel 0: WpT[n][k] = relu(w_s[k]) * W1[k][n]  (bf16, transposed, padded)
// ---------------------------------------------------------------------------
__global__ __launch_bounds__(256) void prep_wpt(const float* __restrict__ w_s,
                                                const float* __restrict__ W1,
                                                unsigned short* __restrict__ wpt) {
    int idx = blockIdx.x * 256 + threadIdx.x;   // 208*1024 total
    int n = idx >> 10, k = idx & (KPAD - 1);
    float v = 0.f;
    if (n < HDIM && k < SDIM) {
        float ws = fmaxf(w_s[k], 0.f);
        v = ws * W1[k * HDIM + n];
    }
    wpt[idx] = f2bf(v);
}

// ---------------------------------------------------------------------------
// Kernel 1: Z = bf16(X) @ WpT^T.  BM=128 (4 waves x 2 m-tiles), BN=208 (13 nt),
// BK=32.  A AND B staged in LDS (double-buffered) -- B re-reads now hit LDS
// instead of L2 (was ~28 GB of L2 traffic), and each B fragment feeds 2 MFMAs.
// ---------------------------------------------------------------------------
__global__ __launch_bounds__(256) void gemm_z(const float* __restrict__ X,
                                              const unsigned short* __restrict__ wpt,
                                              unsigned short* __restrict__ Z) {
    __shared__ __align__(16) unsigned short Abuf[2][128][40];     // 80B row stride: 2-way banks
    __shared__ __align__(16) unsigned short Bbuf[2][13][16][40];
    const int t = threadIdx.x;
    const int m0 = blockIdx.x * 128;
    const int lane = t & 63, w = t >> 6;

    f32x4 acc[2][13];
#pragma unroll
    for (int mt = 0; mt < 2; ++mt)
#pragma unroll
        for (int i = 0; i < 13; ++i) acc[mt][i] = (f32x4){0.f, 0.f, 0.f, 0.f};

    auto stageA = [&](int bsel, int k0) {
        const int row = t >> 1, half = t & 1;
        size_t g = (size_t)(m0 + row) * SDIM + (size_t)(k0 + half * 16);
        float4 f0{}, f1{}, f2{}, f3{};
        if (g + 15 < TOTX) {      // k>=1000 reads next row: finite garbage * zero weight
            f0 = *(const float4*)(X + g);      f1 = *(const float4*)(X + g + 4);
            f2 = *(const float4*)(X + g + 8);  f3 = *(const float4*)(X + g + 12);
        }
        short8 p0, p1;
        p0[0]=(short)f2bf(f0.x); p0[1]=(short)f2bf(f0.y); p0[2]=(short)f2bf(f0.z); p0[3]=(short)f2bf(f0.w);
        p0[4]=(short)f2bf(f1.x); p0[5]=(short)f2bf(f1.y); p0[6]=(short)f2bf(f1.z); p0[7]=(short)f2bf(f1.w);
        p1[0]=(short)f2bf(f2.x); p1[1]=(short)f2bf(f2.y); p1[2]=(short)f2bf(f2.z); p1[3]=(short)f2bf(f2.w);
        p1[4]=(short)f2bf(f3.x); p1[5]=(short)f2bf(f3.y); p1[6]=(short)f2bf(f3.z); p1[7]=(short)f2bf(f3.w);
        *(short8*)&Abuf[bsel][row][half * 16]     = p0;
        *(short8*)&Abuf[bsel][row][half * 16 + 8] = p1;
    };
    auto stageB = [&](int bsel, int k0) {
#pragma unroll
        for (int j = 0; j < 4; ++j) {
            int e = t + 256 * j;                 // 832 chunks: 208 rows x 4 x 8-elem
            if (e < 832) {
                int n = e >> 2, q = e & 3;
                short8 v = *(const short8*)(wpt + (size_t)n * KPAD + k0 + q * 8);
                *(short8*)&Bbuf[bsel][n >> 4][n & 15][q * 8] = v;
            }
        }
    };

    stageA(0, 0);
    stageB(0, 0);
#pragma unroll 1
    for (int it = 0; it < 32; ++it) {
        __syncthreads();
        if (it + 1 < 32) { stageA((it + 1) & 1, (it + 1) * 32); stageB((it + 1) & 1, (it + 1) * 32); }
        const int bsel = it & 1;
        const short8 av0 = *(const short8*)&Abuf[bsel][w * 32 + (lane & 15)][(lane >> 4) * 8];
        const short8 av1 = *(const short8*)&Abuf[bsel][w * 32 + 16 + (lane & 15)][(lane >> 4) * 8];
#pragma unroll
        for (int nt = 0; nt < 13; ++nt) {
            const short8 bv = *(const short8*)&Bbuf[bsel][nt][lane & 15][(lane >> 4) * 8];
            acc[0][nt] = __builtin_amdgcn_mfma_f32_16x16x32_bf16(av0, bv, acc[0][nt], 0, 0, 0);
            acc[1][nt] = __builtin_amdgcn_mfma_f32_16x16x32_bf16(av1, bv, acc[1][nt], 0, 0, 0);
        }
    }

    // C/D layout: col = lane&15, row = (lane>>4)*4 + r
    const int colb = lane & 15;
#pragma unroll
    for (int mt = 0; mt < 2; ++mt) {
        const int rowb = m0 + w * 32 + mt * 16 + (lane >> 4) * 4;
#pragma unroll
        for (int nt = 0; nt < 13; ++nt) {
            int col = nt * 16 + colb;
            if (col < HDIM) {
#pragma unroll
                for (int r = 0; r < 4; ++r)
                    Z[(size_t)(rowb + r) * HDIM + col] = f2bf(acc[mt][nt][r]);
            }
        }
    }
}

// ---------------------------------------------------------------------------
// Kernel 2: sequential scan, 1 WG (256 thr) per batch element.
// Per step: [P2: load km (13 b128, hoisted) | y_{st-1} (hides LDS latency) |
//            mm1 w/ 4 accumulators | pack h]  B1
//           [P3: load h | mm2 w/ 4 accs | tanh | m update | pack km]  B2
// ---------------------------------------------------------------------------
__global__ __launch_bounds__(256, 1) void scan_seq(const unsigned short* __restrict__ Z,
        const float* __restrict__ W1, const float* __restrict__ b1,
        const float* __restrict__ W2, const float* __restrict__ b2,
        const float* __restrict__ Wy, const float* __restrict__ by,
        float* __restrict__ out) {
    __shared__ uint4 km_pk4[13];   // 52 half2: km pairs (k 0..99), [50..51]=0
    __shared__ uint4 h_pk4[26];    // 104 half2: h pairs (k 0..199), [100..103]=0
    __shared__ float m_lds[104];   // m[0..99], [100..103]=0

    const int t = threadIdx.x;
    const int b = blockIdx.x;
    const int n1 = t;
    const int n2 = t >> 1, kc = t & 1;
    const int o = t >> 3, ks = t & 7;

    if (t < 104) m_lds[t] = 0.f;
    if (t < 13) km_pk4[t] = make_uint4(0, 0, 0, 0);
    if (t < 26) h_pk4[t] = make_uint4(0, 0, 0, 0);

    float b1r = (t < HDIM) ? b1[n1] : 0.f;

    half2_t w1r[52];               // W1b column n1, packed (k, k+1)
#pragma unroll
    for (int c = 0; c < 52; ++c) {
        float a0 = 0.f, a1 = 0.f;
        if (t < HDIM && c < 50) {
            a0 = W1[(SDIM + 2 * c) * HDIM + n1];
            a1 = W1[(SDIM + 2 * c + 1) * HDIM + n1];
        }
        w1r[c] = pk2(a0, a1);
    }

    half2_t w2r[52];               // W2 column n2, k-half kc
#pragma unroll
    for (int c = 0; c < 52; ++c) {
        float a0 = 0.f, a1 = 0.f;
        int k0i = kc * 104 + 2 * c;
        if (t < HDIM) {
            if (k0i < HDIM) a0 = W2[k0i * MDIM + n2];
            if (k0i + 1 < HDIM) a1 = W2[(k0i + 1) * MDIM + n2];
        }
        w2r[c] = pk2(a0, a1);
    }

    float kapr = 0.f, cmr = 0.f, b2r = 0.f;
    if (t < HDIM && kc == 0) {     // kappa_m in fp64 to match numpy
        double lg = 1.0000000434294482
                  + (double)n2 * ((2.9999999995657055 - 1.0000000434294482) / 99.0);
        double tau = exp(lg * 2.302585092994046);
        kapr = (float)exp(-1.0 / tau);
        cmr = 3.0f * (1.0f - kapr);
        b2r = b2[n2];
    }

    float wyr[13];
    float byr = 0.f;
#pragma unroll
    for (int i = 0; i < 13; ++i) {
        int k = ks * 13 + i;
        wyr[i] = (t < 80 && k < MDIM) ? Wy[k * 10 + o] : 0.f;
    }
    if (t < 80) byr = by[o];

    const unsigned short* Zb = Z + (size_t)b * TSTEPS * HDIM;
    float* outb = out + (size_t)b * TSTEPS * 10;

    float u = 0.f;
    float m_kmn = 0.f;             // kappa_m * m  (input to the *current* step)
    unsigned short zreg = (t < HDIM) ? Zb[n1] : (unsigned short)0;

    __syncthreads();

#pragma unroll 1
    for (int st = 0; st < TSTEPS; ++st) {
        // ---- P2: hoisted km loads ----
        uint4 kp[13];
#pragma unroll
        for (int c = 0; c < 13; ++c) kp[c] = km_pk4[c];

        // deferred y for step st-1 (independent work hides km-read latency)
        if (st > 0 && t < 80) {
            float p = 0.f;
#pragma unroll
            for (int i = 0; i < 13; ++i) p = fmaf(wyr[i], m_lds[ks * 13 + i], p);
            p += __shfl_xor(p, 1);
            p += __shfl_xor(p, 2);
            p += __shfl_xor(p, 4);
            if (ks == 0) outb[(st - 1) * 10 + o] = p + byr;
        }

        // mm1 -> h, 4 independent accumulator chains
        float h = 0.f;
        if (t < HDIM) {
            u = 0.81873075307798182f * u + bf2f(zreg);   // exp(-1/5)
            int stn = (st + 1 < TSTEPS) ? st + 1 : st;
            zreg = Zb[(size_t)stn * HDIM + n1];          // prefetch next z
            float a0 = u + b1r, a1 = 0.f, a2 = 0.f, a3 = 0.f;
#pragma unroll
            for (int c = 0; c < 13; ++c) {
                a0 = __builtin_amdgcn_fdot2(w1r[4*c+0], as_h2(kp[c].x), a0, false);
                a1 = __builtin_amdgcn_fdot2(w1r[4*c+1], as_h2(kp[c].y), a1, false);
                a2 = __builtin_amdgcn_fdot2(w1r[4*c+2], as_h2(kp[c].z), a2, false);
                a3 = __builtin_amdgcn_fdot2(w1r[4*c+3], as_h2(kp[c].w), a3, false);
            }
            h = fmaxf((a0 + a1) + (a2 + a3), 0.f);
        }
        float ho = __shfl_xor(h, 1);
        if (t < HDIM && kc == 0)
            ((unsigned*)h_pk4)[n2] = as_u32(pk2(h, ho));
        __syncthreads();

        // ---- P3: mm2 -> tanh -> m update; pack km for next step ----
        uint4 hp[13];
#pragma unroll
        for (int c = 0; c < 13; ++c) hp[c] = h_pk4[kc * 13 + c];
        if (t < HDIM) {
            float e0 = 0.f, e1 = 0.f, e2 = 0.f, e3 = 0.f;
#pragma unroll
            for (int c = 0; c < 13; ++c) {
                e0 = __builtin_amdgcn_fdot2(w2r[4*c+0], as_h2(hp[c].x), e0, false);
                e1 = __builtin_amdgcn_fdot2(w2r[4*c+1], as_h2(hp[c].y), e1, false);
                e2 = __builtin_amdgcn_fdot2(w2r[4*c+2], as_h2(hp[c].z), e2, false);
                e3 = __builtin_amdgcn_fdot2(w2r[4*c+3], as_h2(hp[c].w), e3, false);
            }
            float s = (e0 + e1) + (e2 + e3);
            s += __shfl_xor(s, 1);
            if (kc == 0) {
                float x = (s + b2r) * (2.f / 3.f);
                float e = __expf(2.f * x);               // tanh = 1 - 2/(e^{2x}+1)
                float dm = 1.7159f * (1.f - 2.f / (e + 1.f));
                float mnew = m_kmn + cmr * dm;
                m_lds[n2] = mnew;
                m_kmn = kapr * mnew;                     // km for step st+1
            }
        }
        {
            float kmo = __shfl_xor(m_kmn, 2);
            if (t < HDIM && (t & 3) == 0)
                ((unsigned*)km_pk4)[t >> 2] = as_u32(pk2(m_kmn, kmo));
        }
        __syncthreads();
    }

    // final y (step TSTEPS-1)
    if (t < 80) {
        float p = 0.f;
#pragma unroll
        for (int i = 0; i < 13; ++i) p = fmaf(wyr[i], m_lds[ks * 13 + i], p);
        p += __shfl_xor(p, 1);
        p += __shfl_xor(p, 2);
        p += __shfl_xor(p, 4);
        if (ks == 0) outb[(TSTEPS - 1) * 10 + o] = p + byr;
    }
}

extern "C" void kernel_launch(void* const* d_in, const int* in_sizes, int n_in,
                              void* d_out, int out_size, void* d_ws, size_t ws_size,
                              hipStream_t stream) {
    const float* X  = (const float*)d_in[0];
    const float* ws = (const float*)d_in[1];
    const float* W1 = (const float*)d_in[2];
    const float* b1 = (const float*)d_in[3];
    const float* W2 = (const float*)d_in[4];
    const float* b2 = (const float*)d_in[5];
    const float* Wy = (const float*)d_in[6];
    const float* by = (const float*)d_in[7];
    float* out = (float*)d_out;

    unsigned short* wpt = (unsigned short*)d_ws;
    unsigned short* Z   = (unsigned short*)((char*)d_ws + Z_OFF);

    hipLaunchKernelGGL(prep_wpt, dim3((NPAD * KPAD) / 256), dim3(256), 0, stream, ws, W1, wpt);
    hipLaunchKernelGGL(gemm_z, dim3(MT / 128), dim3(256), 0, stream, X, wpt, Z);
    hipLaunchKernelGGL(scan_seq, dim3(BATCH), dim3(256), 0, stream,
                       Z, W1, b1, W2, b2, Wy, by, out);
}

// Round 4
// 1044.042 us; speedup vs baseline: 1.5946x; 1.3446x over previous
//
#include <hip/hip_runtime.h>
#include <math.h>

#define SDIM 1000
#define KPAD 1024
#define HDIM 200
#define MDIM 100
#define NPAD 208
#define TSTEPS 1024
#define BATCH 128
#define MT (BATCH*TSTEPS)
#define TOTX ((size_t)MT*(size_t)SDIM)

// ws layout: [0, 425984) WpT bf16 [208][1024]; [458752, +52428800) Z bf16 [131072][200]
#define Z_OFF 458752

typedef _Float16 half2_t __attribute__((ext_vector_type(2)));
typedef __attribute__((ext_vector_type(8))) short short8;
typedef __attribute__((ext_vector_type(4))) float f32x4;

static __device__ __forceinline__ unsigned short f2bf(float f) {
    unsigned u = __float_as_uint(f);
    unsigned r = 0x7fffu + ((u >> 16) & 1u);   // RNE
    return (unsigned short)((u + r) >> 16);
}
static __device__ __forceinline__ float bf2f(unsigned short h) {
    return __uint_as_float((unsigned)h << 16);
}
static __device__ __forceinline__ half2_t as_h2(unsigned v) {
    union { unsigned u; half2_t h; } c; c.u = v; return c.h;
}
static __device__ __forceinline__ half2_t pk2(float a, float b) {
    half2_t r; r[0] = (_Float16)a; r[1] = (_Float16)b; return r;
}

// ---------------------------------------------------------------------------
// Kernel 0: WpT[n][k] = relu(w_s[k]) * W1[k][n]  (bf16, transposed, padded)
// ---------------------------------------------------------------------------
__global__ __launch_bounds__(256) void prep_wpt(const float* __restrict__ w_s,
                                                const float* __restrict__ W1,
                                                unsigned short* __restrict__ wpt) {
    int idx = blockIdx.x * 256 + threadIdx.x;   // 208*1024 total
    int n = idx >> 10, k = idx & (KPAD - 1);
    float v = 0.f;
    if (n < HDIM && k < SDIM) {
        float ws = fmaxf(w_s[k], 0.f);
        v = ws * W1[k * HDIM + n];
    }
    wpt[idx] = f2bf(v);
}

// ---------------------------------------------------------------------------
// Kernel 1: Z = bf16(X) @ WpT^T.  BM=128 (4 waves x 2 m-tiles), BN=208, BK=32.
// A and B staged in LDS (double-buffered).
// ---------------------------------------------------------------------------
__global__ __launch_bounds__(256) void gemm_z(const float* __restrict__ X,
                                              const unsigned short* __restrict__ wpt,
                                              unsigned short* __restrict__ Z) {
    __shared__ __align__(16) unsigned short Abuf[2][128][40];
    __shared__ __align__(16) unsigned short Bbuf[2][13][16][40];
    const int t = threadIdx.x;
    const int m0 = blockIdx.x * 128;
    const int lane = t & 63, w = t >> 6;

    f32x4 acc[2][13];
#pragma unroll
    for (int mt = 0; mt < 2; ++mt)
#pragma unroll
        for (int i = 0; i < 13; ++i) acc[mt][i] = (f32x4){0.f, 0.f, 0.f, 0.f};

    auto stageA = [&](int bsel, int k0) {
        const int row = t >> 1, half = t & 1;
        size_t g = (size_t)(m0 + row) * SDIM + (size_t)(k0 + half * 16);
        float4 f0{}, f1{}, f2{}, f3{};
        if (g + 15 < TOTX) {
            f0 = *(const float4*)(X + g);      f1 = *(const float4*)(X + g + 4);
            f2 = *(const float4*)(X + g + 8);  f3 = *(const float4*)(X + g + 12);
        }
        short8 p0, p1;
        p0[0]=(short)f2bf(f0.x); p0[1]=(short)f2bf(f0.y); p0[2]=(short)f2bf(f0.z); p0[3]=(short)f2bf(f0.w);
        p0[4]=(short)f2bf(f1.x); p0[5]=(short)f2bf(f1.y); p0[6]=(short)f2bf(f1.z); p0[7]=(short)f2bf(f1.w);
        p1[0]=(short)f2bf(f2.x); p1[1]=(short)f2bf(f2.y); p1[2]=(short)f2bf(f2.z); p1[3]=(short)f2bf(f2.w);
        p1[4]=(short)f2bf(f3.x); p1[5]=(short)f2bf(f3.y); p1[6]=(short)f2bf(f3.z); p1[7]=(short)f2bf(f3.w);
        *(short8*)&Abuf[bsel][row][half * 16]     = p0;
        *(short8*)&Abuf[bsel][row][half * 16 + 8] = p1;
    };
    auto stageB = [&](int bsel, int k0) {
#pragma unroll
        for (int j = 0; j < 4; ++j) {
            int e = t + 256 * j;
            if (e < 832) {
                int n = e >> 2, q = e & 3;
                short8 v = *(const short8*)(wpt + (size_t)n * KPAD + k0 + q * 8);
                *(short8*)&Bbuf[bsel][n >> 4][n & 15][q * 8] = v;
            }
        }
    };

    stageA(0, 0);
    stageB(0, 0);
#pragma unroll 1
    for (int it = 0; it < 32; ++it) {
        __syncthreads();
        if (it + 1 < 32) { stageA((it + 1) & 1, (it + 1) * 32); stageB((it + 1) & 1, (it + 1) * 32); }
        const int bsel = it & 1;
        const short8 av0 = *(const short8*)&Abuf[bsel][w * 32 + (lane & 15)][(lane >> 4) * 8];
        const short8 av1 = *(const short8*)&Abuf[bsel][w * 32 + 16 + (lane & 15)][(lane >> 4) * 8];
#pragma unroll
        for (int nt = 0; nt < 13; ++nt) {
            const short8 bv = *(const short8*)&Bbuf[bsel][nt][lane & 15][(lane >> 4) * 8];
            acc[0][nt] = __builtin_amdgcn_mfma_f32_16x16x32_bf16(av0, bv, acc[0][nt], 0, 0, 0);
            acc[1][nt] = __builtin_amdgcn_mfma_f32_16x16x32_bf16(av1, bv, acc[1][nt], 0, 0, 0);
        }
    }

    const int colb = lane & 15;
#pragma unroll
    for (int mt = 0; mt < 2; ++mt) {
        const int rowb = m0 + w * 32 + mt * 16 + (lane >> 4) * 4;
#pragma unroll
        for (int nt = 0; nt < 13; ++nt) {
            int col = nt * 16 + colb;
            if (col < HDIM) {
#pragma unroll
                for (int r = 0; r < 4; ++r)
                    Z[(size_t)(rowb + r) * HDIM + col] = f2bf(acc[mt][nt][r]);
            }
        }
    }
}

// ---------------------------------------------------------------------------
// Kernel 2: sequential scan, 1 WG (256 thr) per batch element. Shuffle-free.
// P2 (all t<200): h[t] = relu(u + km@W1col_t + b1), one ds_write_b16.
// P3: t<100: full-K mm2 -> tanh -> m (register) -> km fp16 -> km4[cur] (dbuf).
//     t in [200,210): y_{st-1} = km4[prv] @ (Wy/kappa) -- private dot, no shfl.
// 2 barriers/step; no shuffles; m never in LDS.
// ---------------------------------------------------------------------------
__global__ __launch_bounds__(256, 1) void scan_seq(const unsigned short* __restrict__ Z,
        const float* __restrict__ W1, const float* __restrict__ b1,
        const float* __restrict__ W2, const float* __restrict__ b2,
        const float* __restrict__ Wy, const float* __restrict__ by,
        float* __restrict__ out) {
    __shared__ __align__(16) uint4 km4[2][13];    // km fp16 x104 (double-buffered)
    __shared__ __align__(16) uint4 h4[25];        // h  fp16 x200
    __shared__ __align__(16) uint4 wyt4[10][13];  // (Wy/kappa)^T fp16, col o = 104 halfs

    const int t = threadIdx.x;
    const int b = blockIdx.x;

    if (t < 26) ((uint4*)km4)[t] = make_uint4(0, 0, 0, 0);

    // kappa (fp64, matches numpy), per m-index; also used to stage Wy'
    float kapr = 0.f, cmr = 0.f, b2r = 0.f;
    if (t < MDIM) {
        double lg = 1.0000000434294482
                  + (double)t * ((2.9999999995657055 - 1.0000000434294482) / 99.0);
        double tau = exp(lg * 2.302585092994046);
        kapr = (float)exp(-1.0 / tau);
        cmr = 3.0f * (1.0f - kapr);
        b2r = b2[t];
        float inv = 1.0f / kapr;
#pragma unroll
        for (int o = 0; o < 10; ++o)
            ((_Float16*)wyt4[o])[t] = (_Float16)(Wy[t * 10 + o] * inv);
    } else if (t < 104) {
#pragma unroll
        for (int o = 0; o < 10; ++o) ((_Float16*)wyt4[o])[t] = (_Float16)0.f;
    }

    float b1r = (t < HDIM) ? b1[t] : 0.f;

    half2_t w1r[50];               // W1b column t, packed pairs (k, k+1)
#pragma unroll
    for (int c = 0; c < 50; ++c) {
        float a0 = 0.f, a1 = 0.f;
        if (t < HDIM) {
            a0 = W1[(SDIM + 2 * c) * HDIM + t];
            a1 = W1[(SDIM + 2 * c + 1) * HDIM + t];
        }
        w1r[c] = pk2(a0, a1);
    }

    half2_t w2r[100];              // W2 column t (t<100), full K=200 packed
#pragma unroll
    for (int c = 0; c < 100; ++c) {
        float a0 = 0.f, a1 = 0.f;
        if (t < MDIM) {
            a0 = W2[(2 * c) * MDIM + t];
            a1 = W2[(2 * c + 1) * MDIM + t];
        }
        w2r[c] = pk2(a0, a1);
    }

    const int isY = (t >= 200 && t < 210);
    const int o = t - 200;
    float byr = isY ? by[o] : 0.f;

    const unsigned short* Zb = Z + (size_t)b * TSTEPS * HDIM;
    float* outb = out + (size_t)b * TSTEPS * 10;

    float u = 0.f;
    float m_kmn = 0.f;             // kappa_m * m (input to current step)
    unsigned short zreg = (t < HDIM) ? Zb[t] : (unsigned short)0;

    __syncthreads();

#pragma unroll 1
    for (int st = 0; st < TSTEPS; ++st) {
        const int cur = st & 1, prv = cur ^ 1;

        // ---- P2: mm1 -> h (all output threads), km read from buffer prv ----
        if (t < HDIM) {
            uint4 kp[13];
#pragma unroll
            for (int c = 0; c < 13; ++c) kp[c] = km4[prv][c];
            u = 0.81873075307798182f * u + bf2f(zreg);     // exp(-1/5)
            int stn = (st + 1 < TSTEPS) ? st + 1 : st;
            zreg = Zb[(size_t)stn * HDIM + t];             // prefetch next z
            float a0 = u + b1r, a1 = 0.f, a2 = 0.f, a3 = 0.f;
#pragma unroll
            for (int c = 0; c < 13; ++c) {
                a0 = __builtin_amdgcn_fdot2(w1r[(4*c+0) % 50], as_h2(kp[c].x), a0, false);
                a1 = __builtin_amdgcn_fdot2(w1r[(4*c+1) % 50], as_h2(kp[c].y), a1, false);
                a2 = (4*c+2 < 50) ? __builtin_amdgcn_fdot2(w1r[4*c+2], as_h2(kp[c].z), a2, false) : a2;
                a3 = (4*c+3 < 50) ? __builtin_amdgcn_fdot2(w1r[4*c+3], as_h2(kp[c].w), a3, false) : a3;
            }
            float h = fmaxf((a0 + a1) + (a2 + a3), 0.f);
            ((_Float16*)h4)[t] = (_Float16)h;
        }
        __syncthreads();

        // ---- P3a: mm2 full-K on t<100 -> tanh -> m update -> km write ----
        if (t < MDIM) {
            float e0 = 0.f, e1 = 0.f, e2 = 0.f, e3 = 0.f;
            uint4 hpA[13];
#pragma unroll
            for (int c = 0; c < 13; ++c) hpA[c] = h4[c];
#pragma unroll
            for (int c = 0; c < 13; ++c) {
                e0 = __builtin_amdgcn_fdot2(w2r[4*c+0], as_h2(hpA[c].x), e0, false);
                e1 = __builtin_amdgcn_fdot2(w2r[4*c+1], as_h2(hpA[c].y), e1, false);
                e2 = __builtin_amdgcn_fdot2(w2r[4*c+2], as_h2(hpA[c].z), e2, false);
                e3 = __builtin_amdgcn_fdot2(w2r[4*c+3], as_h2(hpA[c].w), e3, false);
            }
            uint4 hpB[12];
#pragma unroll
            for (int c = 0; c < 12; ++c) hpB[c] = h4[13 + c];
#pragma unroll
            for (int c = 0; c < 12; ++c) {
                e0 = __builtin_amdgcn_fdot2(w2r[52+4*c+0], as_h2(hpB[c].x), e0, false);
                e1 = __builtin_amdgcn_fdot2(w2r[52+4*c+1], as_h2(hpB[c].y), e1, false);
                e2 = __builtin_amdgcn_fdot2(w2r[52+4*c+2], as_h2(hpB[c].z), e2, false);
                e3 = __builtin_amdgcn_fdot2(w2r[52+4*c+3], as_h2(hpB[c].w), e3, false);
            }
            float s = (e0 + e1) + (e2 + e3);
            float x = (s + b2r) * (2.f / 3.f);
            float e = __expf(2.f * x);                     // tanh = 1 - 2/(e^{2x}+1)
            float dm = 1.7159f * (1.f - 2.f / (e + 1.f));
            float mnew = m_kmn + cmr * dm;                 // m_t
            m_kmn = kapr * mnew;                           // km_{t+1}
            ((_Float16*)km4[cur])[t] = (_Float16)m_kmn;
        }

        // ---- P3b: y_{st-1} on wave 3 (t 200..209), km buffer prv, no shfl --
        if (isY && st > 0) {
            uint4 kmv[13], wyv[13];
#pragma unroll
            for (int c = 0; c < 13; ++c) { kmv[c] = km4[prv][c]; wyv[c] = wyt4[o][c]; }
            float p0 = 0.f, p1 = 0.f, p2 = 0.f, p3 = 0.f;
#pragma unroll
            for (int c = 0; c < 13; ++c) {
                p0 = __builtin_amdgcn_fdot2(as_h2(wyv[c].x), as_h2(kmv[c].x), p0, false);
                p1 = __builtin_amdgcn_fdot2(as_h2(wyv[c].y), as_h2(kmv[c].y), p1, false);
                p2 = __builtin_amdgcn_fdot2(as_h2(wyv[c].z), as_h2(kmv[c].z), p2, false);
                p3 = __builtin_amdgcn_fdot2(as_h2(wyv[c].w), as_h2(kmv[c].w), p3, false);
            }
            outb[(size_t)(st - 1) * 10 + o] = (p0 + p1) + (p2 + p3) + byr;
        }
        __syncthreads();
    }

    // final y (step TSTEPS-1): km buffer cur at st=1023 -> index 1
    if (isY) {
        uint4 kmv[13], wyv[13];
#pragma unroll
        for (int c = 0; c < 13; ++c) { kmv[c] = km4[1][c]; wyv[c] = wyt4[o][c]; }
        float p0 = 0.f, p1 = 0.f, p2 = 0.f, p3 = 0.f;
#pragma unroll
        for (int c = 0; c < 13; ++c) {
            p0 = __builtin_amdgcn_fdot2(as_h2(wyv[c].x), as_h2(kmv[c].x), p0, false);
            p1 = __builtin_amdgcn_fdot2(as_h2(wyv[c].y), as_h2(kmv[c].y), p1, false);
            p2 = __builtin_amdgcn_fdot2(as_h2(wyv[c].z), as_h2(kmv[c].z), p2, false);
            p3 = __builtin_amdgcn_fdot2(as_h2(wyv[c].w), as_h2(kmv[c].w), p3, false);
        }
        outb[(size_t)(TSTEPS - 1) * 10 + o] = (p0 + p1) + (p2 + p3) + byr;
    }
}

extern "C" void kernel_launch(void* const* d_in, const int* in_sizes, int n_in,
                              void* d_out, int out_size, void* d_ws, size_t ws_size,
                              hipStream_t stream) {
    const float* X  = (const float*)d_in[0];
    const float* ws = (const float*)d_in[1];
    const float* W1 = (const float*)d_in[2];
    const float* b1 = (const float*)d_in[3];
    const float* W2 = (const float*)d_in[4];
    const float* b2 = (const float*)d_in[5];
    const float* Wy = (const float*)d_in[6];
    const float* by = (const float*)d_in[7];
    float* out = (float*)d_out;

    unsigned short* wpt = (unsigned short*)d_ws;
    unsigned short* Z   = (unsigned short*)((char*)d_ws + Z_OFF);

    hipLaunchKernelGGL(prep_wpt, dim3((NPAD * KPAD) / 256), dim3(256), 0, stream, ws, W1, wpt);
    hipLaunchKernelGGL(gemm_z, dim3(MT / 128), dim3(256), 0, stream, X, wpt, Z);
    hipLaunchKernelGGL(scan_seq, dim3(BATCH), dim3(256), 0, stream,
                       Z, W1, b1, W2, b2, Wy, by, out);
}

// Round 5
// 1043.892 us; speedup vs baseline: 1.5949x; 1.0001x over previous
//
#include <hip/hip_runtime.h>
#include <math.h>

#define SDIM 1000
#define KPAD 1024
#define HDIM 200
#define MDIM 100
#define NPAD 208
#define TSTEPS 1024
#define BATCH 128
#define MT (BATCH*TSTEPS)
#define TOTX ((size_t)MT*(size_t)SDIM)

// ws layout: [0, 425984) WpT bf16 [208][1024]; [458752, +52428800) Z bf16 [131072][200]
#define Z_OFF 458752

typedef _Float16 half2_t __attribute__((ext_vector_type(2)));
typedef __attribute__((ext_vector_type(8))) short short8;
typedef __attribute__((ext_vector_type(4))) float f32x4;

static __device__ __forceinline__ unsigned short f2bf(float f) {
    unsigned u = __float_as_uint(f);
    unsigned r = 0x7fffu + ((u >> 16) & 1u);   // RNE
    return (unsigned short)((u + r) >> 16);
}
static __device__ __forceinline__ float bf2f(unsigned short h) {
    return __uint_as_float((unsigned)h << 16);
}
static __device__ __forceinline__ half2_t as_h2(unsigned v) {
    union { unsigned u; half2_t h; } c; c.u = v; return c.h;
}
static __device__ __forceinline__ half2_t pk2(float a, float b) {
    half2_t r; r[0] = (_Float16)a; r[1] = (_Float16)b; return r;
}

// Raw workgroup barrier: drains ONLY lgkm (LDS) -- global loads/stores stay
// in flight across it (unlike __syncthreads, which drains vmcnt(0) and was
// serializing the z-prefetch and y-store latency into every step).
static __device__ __forceinline__ void wg_barrier() {
    asm volatile("s_waitcnt lgkmcnt(0)" ::: "memory");
    __builtin_amdgcn_s_barrier();
    asm volatile("" ::: "memory");
}

// ---------------------------------------------------------------------------
// Kernel 0: WpT[n][k] = relu(w_s[k]) * W1[k][n]  (bf16, transposed, padded)
// ---------------------------------------------------------------------------
__global__ __launch_bounds__(256) void prep_wpt(const float* __restrict__ w_s,
                                                const float* __restrict__ W1,
                                                unsigned short* __restrict__ wpt) {
    int idx = blockIdx.x * 256 + threadIdx.x;   // 208*1024 total
    int n = idx >> 10, k = idx & (KPAD - 1);
    float v = 0.f;
    if (n < HDIM && k < SDIM) {
        float ws = fmaxf(w_s[k], 0.f);
        v = ws * W1[k * HDIM + n];
    }
    wpt[idx] = f2bf(v);
}

// ---------------------------------------------------------------------------
// Kernel 1: Z = bf16(X) @ WpT^T.  BM=128 (4 waves x 2 m-tiles), BN=208, BK=32.
// A and B staged in LDS (double-buffered).
// ---------------------------------------------------------------------------
__global__ __launch_bounds__(256) void gemm_z(const float* __restrict__ X,
                                              const unsigned short* __restrict__ wpt,
                                              unsigned short* __restrict__ Z) {
    __shared__ __align__(16) unsigned short Abuf[2][128][40];
    __shared__ __align__(16) unsigned short Bbuf[2][13][16][40];
    const int t = threadIdx.x;
    const int m0 = blockIdx.x * 128;
    const int lane = t & 63, w = t >> 6;

    f32x4 acc[2][13];
#pragma unroll
    for (int mt = 0; mt < 2; ++mt)
#pragma unroll
        for (int i = 0; i < 13; ++i) acc[mt][i] = (f32x4){0.f, 0.f, 0.f, 0.f};

    auto stageA = [&](int bsel, int k0) {
        const int row = t >> 1, half = t & 1;
        size_t g = (size_t)(m0 + row) * SDIM + (size_t)(k0 + half * 16);
        float4 f0{}, f1{}, f2{}, f3{};
        if (g + 15 < TOTX) {
            f0 = *(const float4*)(X + g);      f1 = *(const float4*)(X + g + 4);
            f2 = *(const float4*)(X + g + 8);  f3 = *(const float4*)(X + g + 12);
        }
        short8 p0, p1;
        p0[0]=(short)f2bf(f0.x); p0[1]=(short)f2bf(f0.y); p0[2]=(short)f2bf(f0.z); p0[3]=(short)f2bf(f0.w);
        p0[4]=(short)f2bf(f1.x); p0[5]=(short)f2bf(f1.y); p0[6]=(short)f2bf(f1.z); p0[7]=(short)f2bf(f1.w);
        p1[0]=(short)f2bf(f2.x); p1[1]=(short)f2bf(f2.y); p1[2]=(short)f2bf(f2.z); p1[3]=(short)f2bf(f2.w);
        p1[4]=(short)f2bf(f3.x); p1[5]=(short)f2bf(f3.y); p1[6]=(short)f2bf(f3.z); p1[7]=(short)f2bf(f3.w);
        *(short8*)&Abuf[bsel][row][half * 16]     = p0;
        *(short8*)&Abuf[bsel][row][half * 16 + 8] = p1;
    };
    auto stageB = [&](int bsel, int k0) {
#pragma unroll
        for (int j = 0; j < 4; ++j) {
            int e = t + 256 * j;
            if (e < 832) {
                int n = e >> 2, q = e & 3;
                short8 v = *(const short8*)(wpt + (size_t)n * KPAD + k0 + q * 8);
                *(short8*)&Bbuf[bsel][n >> 4][n & 15][q * 8] = v;
            }
        }
    };

    stageA(0, 0);
    stageB(0, 0);
#pragma unroll 1
    for (int it = 0; it < 32; ++it) {
        __syncthreads();
        if (it + 1 < 32) { stageA((it + 1) & 1, (it + 1) * 32); stageB((it + 1) & 1, (it + 1) * 32); }
        const int bsel = it & 1;
        const short8 av0 = *(const short8*)&Abuf[bsel][w * 32 + (lane & 15)][(lane >> 4) * 8];
        const short8 av1 = *(const short8*)&Abuf[bsel][w * 32 + 16 + (lane & 15)][(lane >> 4) * 8];
#pragma unroll
        for (int nt = 0; nt < 13; ++nt) {
            const short8 bv = *(const short8*)&Bbuf[bsel][nt][lane & 15][(lane >> 4) * 8];
            acc[0][nt] = __builtin_amdgcn_mfma_f32_16x16x32_bf16(av0, bv, acc[0][nt], 0, 0, 0);
            acc[1][nt] = __builtin_amdgcn_mfma_f32_16x16x32_bf16(av1, bv, acc[1][nt], 0, 0, 0);
        }
    }

    const int colb = lane & 15;
#pragma unroll
    for (int mt = 0; mt < 2; ++mt) {
        const int rowb = m0 + w * 32 + mt * 16 + (lane >> 4) * 4;
#pragma unroll
        for (int nt = 0; nt < 13; ++nt) {
            int col = nt * 16 + colb;
            if (col < HDIM) {
#pragma unroll
                for (int r = 0; r < 4; ++r)
                    Z[(size_t)(rowb + r) * HDIM + col] = f2bf(acc[mt][nt][r]);
            }
        }
    }
}

// ---------------------------------------------------------------------------
// Kernel 2: sequential scan, 1 WG (256 thr) per batch element. Shuffle-free.
// Raw lgkm-only barriers (z-loads / y-stores stay in flight); loop unrolled x2
// so km double-buffer indices are compile-time and z is prefetched 2 steps out.
// ---------------------------------------------------------------------------
__global__ __launch_bounds__(256, 1) void scan_seq(const unsigned short* __restrict__ Z,
        const float* __restrict__ W1, const float* __restrict__ b1,
        const float* __restrict__ W2, const float* __restrict__ b2,
        const float* __restrict__ Wy, const float* __restrict__ by,
        float* __restrict__ out) {
    __shared__ __align__(16) uint4 km4[2][13];    // km fp16 x104 (double-buffered)
    __shared__ __align__(16) uint4 h4[25];        // h  fp16 x200
    __shared__ __align__(16) uint4 wyt4[10][13];  // (Wy/kappa)^T fp16, col o

    const int t = threadIdx.x;
    const int b = blockIdx.x;

    if (t < 26) ((uint4*)km4)[t] = make_uint4(0, 0, 0, 0);

    float kapr = 0.f, cmr = 0.f, b2r = 0.f;
    if (t < MDIM) {                // kappa_m in fp64 to match numpy
        double lg = 1.0000000434294482
                  + (double)t * ((2.9999999995657055 - 1.0000000434294482) / 99.0);
        double tau = exp(lg * 2.302585092994046);
        kapr = (float)exp(-1.0 / tau);
        cmr = 3.0f * (1.0f - kapr);
        b2r = b2[t];
        float inv = 1.0f / kapr;
#pragma unroll
        for (int o = 0; o < 10; ++o)
            ((_Float16*)wyt4[o])[t] = (_Float16)(Wy[t * 10 + o] * inv);
    } else if (t < 104) {
#pragma unroll
        for (int o = 0; o < 10; ++o) ((_Float16*)wyt4[o])[t] = (_Float16)0.f;
    }

    float b1r = (t < HDIM) ? b1[t] : 0.f;

    half2_t w1r[50];               // W1b column t, packed pairs (k, k+1)
#pragma unroll
    for (int c = 0; c < 50; ++c) {
        float a0 = 0.f, a1 = 0.f;
        if (t < HDIM) {
            a0 = W1[(SDIM + 2 * c) * HDIM + t];
            a1 = W1[(SDIM + 2 * c + 1) * HDIM + t];
        }
        w1r[c] = pk2(a0, a1);
    }

    half2_t w2r[100];              // W2 column t (t<100), full K=200 packed
#pragma unroll
    for (int c = 0; c < 100; ++c) {
        float a0 = 0.f, a1 = 0.f;
        if (t < MDIM) {
            a0 = W2[(2 * c) * MDIM + t];
            a1 = W2[(2 * c + 1) * MDIM + t];
        }
        w2r[c] = pk2(a0, a1);
    }

    const int isY = (t >= 200 && t < 210);
    const int o = t - 200;
    float byr = isY ? by[o] : 0.f;

    const unsigned short* Zb = Z + (size_t)b * TSTEPS * HDIM;
    float* outb = out + (size_t)b * TSTEPS * 10;

    float u = 0.f;
    float m_kmn = 0.f;             // kappa_m * m (input to current step)
    unsigned short zA = 0, zB = 0; // z for even / odd steps (2-ahead prefetch)
    if (t < HDIM) { zA = Zb[t]; zB = Zb[HDIM + t]; }

    __syncthreads();

    // one step; CUR/PRV become compile-time after inlining (called with literals)
    auto step = [&](const int CUR, const int PRV, unsigned short& zreg, const int st) {
        // ---- P2: mm1 -> h ----
        if (t < HDIM) {
            uint4 kp[13];
#pragma unroll
            for (int c = 0; c < 13; ++c) kp[c] = km4[PRV][c];
            u = 0.81873075307798182f * u + bf2f(zreg);     // exp(-1/5)
            int stn = st + 2; stn = (stn < TSTEPS) ? stn : TSTEPS - 1;
            zreg = Zb[(size_t)stn * HDIM + t];             // 2-step-ahead prefetch
            float a0 = u + b1r, a1 = 0.f, a2 = 0.f, a3 = 0.f;
#pragma unroll
            for (int c = 0; c < 13; ++c) {
                a0 = __builtin_amdgcn_fdot2(w1r[(4*c+0) % 50], as_h2(kp[c].x), a0, false);
                a1 = __builtin_amdgcn_fdot2(w1r[(4*c+1) % 50], as_h2(kp[c].y), a1, false);
                a2 = (4*c+2 < 50) ? __builtin_amdgcn_fdot2(w1r[4*c+2], as_h2(kp[c].z), a2, false) : a2;
                a3 = (4*c+3 < 50) ? __builtin_amdgcn_fdot2(w1r[4*c+3], as_h2(kp[c].w), a3, false) : a3;
            }
            float h = fmaxf((a0 + a1) + (a2 + a3), 0.f);
            ((_Float16*)h4)[t] = (_Float16)h;
        }
        wg_barrier();

        // ---- P3a: mm2 full-K on t<100 -> tanh -> m update -> km write ----
        if (t < MDIM) {
            float e0 = 0.f, e1 = 0.f, e2 = 0.f, e3 = 0.f;
            uint4 hpA[13];
#pragma unroll
            for (int c = 0; c < 13; ++c) hpA[c] = h4[c];
#pragma unroll
            for (int c = 0; c < 13; ++c) {
                e0 = __builtin_amdgcn_fdot2(w2r[4*c+0], as_h2(hpA[c].x), e0, false);
                e1 = __builtin_amdgcn_fdot2(w2r[4*c+1], as_h2(hpA[c].y), e1, false);
                e2 = __builtin_amdgcn_fdot2(w2r[4*c+2], as_h2(hpA[c].z), e2, false);
                e3 = __builtin_amdgcn_fdot2(w2r[4*c+3], as_h2(hpA[c].w), e3, false);
            }
            uint4 hpB[12];
#pragma unroll
            for (int c = 0; c < 12; ++c) hpB[c] = h4[13 + c];
#pragma unroll
            for (int c = 0; c < 12; ++c) {
                e0 = __builtin_amdgcn_fdot2(w2r[52+4*c+0], as_h2(hpB[c].x), e0, false);
                e1 = __builtin_amdgcn_fdot2(w2r[52+4*c+1], as_h2(hpB[c].y), e1, false);
                e2 = __builtin_amdgcn_fdot2(w2r[52+4*c+2], as_h2(hpB[c].z), e2, false);
                e3 = __builtin_amdgcn_fdot2(w2r[52+4*c+3], as_h2(hpB[c].w), e3, false);
            }
            float s = (e0 + e1) + (e2 + e3);
            float x = (s + b2r) * (2.f / 3.f);
            float e = __expf(2.f * x);                     // tanh = 1 - 2/(e^{2x}+1)
            float dm = 1.7159f * (1.f - 2.f / (e + 1.f));
            float mnew = m_kmn + cmr * dm;                 // m_t
            m_kmn = kapr * mnew;                           // km_{t+1}
            ((_Float16*)km4[CUR])[t] = (_Float16)m_kmn;
        }

        // ---- P3b: y_{st-1} on wave 3 (t 200..209), km buffer PRV ----
        if (isY && st > 0) {
            uint4 kmv[13], wyv[13];
#pragma unroll
            for (int c = 0; c < 13; ++c) { kmv[c] = km4[PRV][c]; wyv[c] = wyt4[o][c]; }
            float p0 = 0.f, p1 = 0.f, p2 = 0.f, p3 = 0.f;
#pragma unroll
            for (int c = 0; c < 13; ++c) {
                p0 = __builtin_amdgcn_fdot2(as_h2(wyv[c].x), as_h2(kmv[c].x), p0, false);
                p1 = __builtin_amdgcn_fdot2(as_h2(wyv[c].y), as_h2(kmv[c].y), p1, false);
                p2 = __builtin_amdgcn_fdot2(as_h2(wyv[c].z), as_h2(kmv[c].z), p2, false);
                p3 = __builtin_amdgcn_fdot2(as_h2(wyv[c].w), as_h2(kmv[c].w), p3, false);
            }
            outb[(size_t)(st - 1) * 10 + o] = (p0 + p1) + (p2 + p3) + byr;
        }
        wg_barrier();
    };

#pragma unroll 1
    for (int st = 0; st < TSTEPS; st += 2) {
        step(0, 1, zA, st);        // even: write km4[0], read km4[1]
        step(1, 0, zB, st + 1);    // odd:  write km4[1], read km4[0]
    }

    // final y (step TSTEPS-1): km written to buffer 1 at st=1023
    if (isY) {
        uint4 kmv[13], wyv[13];
#pragma unroll
        for (int c = 0; c < 13; ++c) { kmv[c] = km4[1][c]; wyv[c] = wyt4[o][c]; }
        float p0 = 0.f, p1 = 0.f, p2 = 0.f, p3 = 0.f;
#pragma unroll
        for (int c = 0; c < 13; ++c) {
            p0 = __builtin_amdgcn_fdot2(as_h2(wyv[c].x), as_h2(kmv[c].x), p0, false);
            p1 = __builtin_amdgcn_fdot2(as_h2(wyv[c].y), as_h2(kmv[c].y), p1, false);
            p2 = __builtin_amdgcn_fdot2(as_h2(wyv[c].z), as_h2(kmv[c].z), p2, false);
            p3 = __builtin_amdgcn_fdot2(as_h2(wyv[c].w), as_h2(kmv[c].w), p3, false);
        }
        outb[(size_t)(TSTEPS - 1) * 10 + o] = (p0 + p1) + (p2 + p3) + byr;
    }
}

extern "C" void kernel_launch(void* const* d_in, const int* in_sizes, int n_in,
                              void* d_out, int out_size, void* d_ws, size_t ws_size,
                              hipStream_t stream) {
    const float* X  = (const float*)d_in[0];
    const float* ws = (const float*)d_in[1];
    const float* W1 = (const float*)d_in[2];
    const float* b1 = (const float*)d_in[3];
    const float* W2 = (const float*)d_in[4];
    const float* b2 = (const float*)d_in[5];
    const float* Wy = (const float*)d_in[6];
    const float* by = (const float*)d_in[7];
    float* out = (float*)d_out;

    unsigned short* wpt = (unsigned short*)d_ws;
    unsigned short* Z   = (unsigned short*)((char*)d_ws + Z_OFF);

    hipLaunchKernelGGL(prep_wpt, dim3((NPAD * KPAD) / 256), dim3(256), 0, stream, ws, W1, wpt);
    hipLaunchKernelGGL(gemm_z, dim3(MT / 128), dim3(256), 0, stream, X, wpt, Z);
    hipLaunchKernelGGL(scan_seq, dim3(BATCH), dim3(256), 0, stream,
                       Z, W1, b1, W2, b2, Wy, by, out);
}

// Round 6
// 1039.901 us; speedup vs baseline: 1.6010x; 1.0038x over previous
//
#include <hip/hip_runtime.h>
#include <math.h>

#define SDIM 1000
#define KPAD 1024
#define HDIM 200
#define MDIM 100
#define NPAD 208
#define TSTEPS 1024
#define BATCH 128
#define MT (BATCH*TSTEPS)
#define TOTX ((size_t)MT*(size_t)SDIM)

// ws layout: [0, 425984) WpT bf16 [208][1024]; [458752, +52428800) Z bf16 [131072][200]
#define Z_OFF 458752

typedef _Float16 half2_t __attribute__((ext_vector_type(2)));
typedef __attribute__((ext_vector_type(8))) short short8;
typedef __attribute__((ext_vector_type(4))) float f32x4;

static __device__ __forceinline__ unsigned short f2bf(float f) {
    unsigned u = __float_as_uint(f);
    unsigned r = 0x7fffu + ((u >> 16) & 1u);   // RNE
    return (unsigned short)((u + r) >> 16);
}
static __device__ __forceinline__ float bf2f(unsigned short h) {
    return __uint_as_float((unsigned)h << 16);
}
static __device__ __forceinline__ half2_t as_h2(unsigned v) {
    union { unsigned u; half2_t h; } c; c.u = v; return c.h;
}
static __device__ __forceinline__ unsigned as_u32(half2_t h) {
    union { half2_t h; unsigned u; } c; c.h = h; return c.u;
}
static __device__ __forceinline__ half2_t pk2(float a, float b) {
    half2_t r; r[0] = (_Float16)a; r[1] = (_Float16)b; return r;
}

// Raw workgroup barrier: drains ONLY lgkm (LDS); global ops stay in flight.
static __device__ __forceinline__ void wg_barrier() {
    asm volatile("s_waitcnt lgkmcnt(0)" ::: "memory");
    __builtin_amdgcn_s_barrier();
    asm volatile("" ::: "memory");
}

// ---------------------------------------------------------------------------
// Kernel 0: WpT[n][k] = relu(w_s[k]) * W1[k][n]  (bf16, transposed, padded)
// ---------------------------------------------------------------------------
__global__ __launch_bounds__(256) void prep_wpt(const float* __restrict__ w_s,
                                                const float* __restrict__ W1,
                                                unsigned short* __restrict__ wpt) {
    int idx = blockIdx.x * 256 + threadIdx.x;   // 208*1024 total
    int n = idx >> 10, k = idx & (KPAD - 1);
    float v = 0.f;
    if (n < HDIM && k < SDIM) {
        float ws = fmaxf(w_s[k], 0.f);
        v = ws * W1[k * HDIM + n];
    }
    wpt[idx] = f2bf(v);
}

// ---------------------------------------------------------------------------
// Kernel 1: Z = bf16(X) @ WpT^T.  BM=128 (4 waves x 2 m-tiles), BN=208, BK=32.
// A and B staged in LDS (double-buffered).  (unchanged)
// ---------------------------------------------------------------------------
__global__ __launch_bounds__(256) void gemm_z(const float* __restrict__ X,
                                              const unsigned short* __restrict__ wpt,
                                              unsigned short* __restrict__ Z) {
    __shared__ __align__(16) unsigned short Abuf[2][128][40];
    __shared__ __align__(16) unsigned short Bbuf[2][13][16][40];
    const int t = threadIdx.x;
    const int m0 = blockIdx.x * 128;
    const int lane = t & 63, w = t >> 6;

    f32x4 acc[2][13];
#pragma unroll
    for (int mt = 0; mt < 2; ++mt)
#pragma unroll
        for (int i = 0; i < 13; ++i) acc[mt][i] = (f32x4){0.f, 0.f, 0.f, 0.f};

    auto stageA = [&](int bsel, int k0) {
        const int row = t >> 1, half = t & 1;
        size_t g = (size_t)(m0 + row) * SDIM + (size_t)(k0 + half * 16);
        float4 f0{}, f1{}, f2{}, f3{};
        if (g + 15 < TOTX) {
            f0 = *(const float4*)(X + g);      f1 = *(const float4*)(X + g + 4);
            f2 = *(const float4*)(X + g + 8);  f3 = *(const float4*)(X + g + 12);
        }
        short8 p0, p1;
        p0[0]=(short)f2bf(f0.x); p0[1]=(short)f2bf(f0.y); p0[2]=(short)f2bf(f0.z); p0[3]=(short)f2bf(f0.w);
        p0[4]=(short)f2bf(f1.x); p0[5]=(short)f2bf(f1.y); p0[6]=(short)f2bf(f1.z); p0[7]=(short)f2bf(f1.w);
        p1[0]=(short)f2bf(f2.x); p1[1]=(short)f2bf(f2.y); p1[2]=(short)f2bf(f2.z); p1[3]=(short)f2bf(f2.w);
        p1[4]=(short)f2bf(f3.x); p1[5]=(short)f2bf(f3.y); p1[6]=(short)f2bf(f3.z); p1[7]=(short)f2bf(f3.w);
        *(short8*)&Abuf[bsel][row][half * 16]     = p0;
        *(short8*)&Abuf[bsel][row][half * 16 + 8] = p1;
    };
    auto stageB = [&](int bsel, int k0) {
#pragma unroll
        for (int j = 0; j < 4; ++j) {
            int e = t + 256 * j;
            if (e < 832) {
                int n = e >> 2, q = e & 3;
                short8 v = *(const short8*)(wpt + (size_t)n * KPAD + k0 + q * 8);
                *(short8*)&Bbuf[bsel][n >> 4][n & 15][q * 8] = v;
            }
        }
    };

    stageA(0, 0);
    stageB(0, 0);
#pragma unroll 1
    for (int it = 0; it < 32; ++it) {
        __syncthreads();
        if (it + 1 < 32) { stageA((it + 1) & 1, (it + 1) * 32); stageB((it + 1) & 1, (it + 1) * 32); }
        const int bsel = it & 1;
        const short8 av0 = *(const short8*)&Abuf[bsel][w * 32 + (lane & 15)][(lane >> 4) * 8];
        const short8 av1 = *(const short8*)&Abuf[bsel][w * 32 + 16 + (lane & 15)][(lane >> 4) * 8];
#pragma unroll
        for (int nt = 0; nt < 13; ++nt) {
            const short8 bv = *(const short8*)&Bbuf[bsel][nt][lane & 15][(lane >> 4) * 8];
            acc[0][nt] = __builtin_amdgcn_mfma_f32_16x16x32_bf16(av0, bv, acc[0][nt], 0, 0, 0);
            acc[1][nt] = __builtin_amdgcn_mfma_f32_16x16x32_bf16(av1, bv, acc[1][nt], 0, 0, 0);
        }
    }

    const int colb = lane & 15;
#pragma unroll
    for (int mt = 0; mt < 2; ++mt) {
        const int rowb = m0 + w * 32 + mt * 16 + (lane >> 4) * 4;
#pragma unroll
        for (int nt = 0; nt < 13; ++nt) {
            int col = nt * 16 + colb;
            if (col < HDIM) {
#pragma unroll
                for (int r = 0; r < 4; ++r)
                    Z[(size_t)(rowb + r) * HDIM + col] = f2bf(acc[mt][nt][r]);
            }
        }
    }
}

// ---------------------------------------------------------------------------
// Kernel 2: sequential scan, 1 WG (256 thr) per batch element.
// ONE barrier per step; broadcasts via v_readlane->SGPR, never LDS.
//  - h ownership: wave w, lane i<50 owns h[50w+i]; u,z in-lane.
//  - mm1: h = relu(u + b1 + sum_k m_k * (kap_k*W1b[k][n]))  (kappa folded in W1)
//    y-cols (wave0 lanes 50-59) share the same dot block with Wy weights.
//  - h broadcast in-wave: shfl_xor(1) pack -> 25 readlanes -> sgpr.
//  - mm2 k-split by wave: wave w accumulates partial a2[j] over its 50 h's
//    for 2 cols/lane; one ds_write_b64 of partials; barrier.
//  - every lane reads 4 partials/col, sums, tanh, updates m[2l],m[2l+1]
//    redundantly in all waves; 50 readlanes publish m pairs to sgpr.
// ---------------------------------------------------------------------------
__global__ __launch_bounds__(256, 1) void scan_seq(const unsigned short* __restrict__ Z,
        const float* __restrict__ W1, const float* __restrict__ b1,
        const float* __restrict__ W2, const float* __restrict__ b2,
        const float* __restrict__ Wy, const float* __restrict__ by,
        float* __restrict__ out) {
    __shared__ __align__(16) float part[2][4][104];   // [buf][wave][col] partial a2
    __shared__ float kap_s[104], cm_s[104];

    const int t = threadIdx.x;
    const int b = blockIdx.x;
    const int w = t >> 6, lane = t & 63;
    const int n = 50 * w + lane;            // owned h column (lane<50)
    const bool hAct = lane < 50;
    const bool yAct = (w == 0) && (lane >= 50 && lane < 60);
    const int o = lane - 50;

    if (t < 104) {
        float kv = 0.f, cv = 0.f;
        if (t < MDIM) {                     // kappa_m in fp64 to match numpy
            double lg = 1.0000000434294482
                      + (double)t * ((2.9999999995657055 - 1.0000000434294482) / 99.0);
            double tau = exp(lg * 2.302585092994046);
            kv = (float)exp(-1.0 / tau);
            cv = 3.0f * (1.0f - kv);
        }
        kap_s[t] = kv; cm_s[t] = cv;
    }
    __syncthreads();

    // mm1 / y weights (shared dot block): 50 half2 pairs over k=0..99 (m-index)
    half2_t w1r[50];
#pragma unroll
    for (int c = 0; c < 50; ++c) {
        float a0 = 0.f, a1 = 0.f;
        if (hAct) {
            a0 = kap_s[2 * c]     * W1[(SDIM + 2 * c)     * HDIM + n];
            a1 = kap_s[2 * c + 1] * W1[(SDIM + 2 * c + 1) * HDIM + n];
        } else if (yAct) {
            a0 = Wy[(2 * c) * 10 + o];
            a1 = Wy[(2 * c + 1) * 10 + o];
        }
        w1r[c] = pk2(a0, a1);
    }
    float base_b = hAct ? b1[n] : (yAct ? by[o] : 0.f);

    // mm2 partial weights: wave w's k-range [50w, 50w+50), cols j0=2*lane, j1=2*lane+1
    const int j0 = 2 * lane, j1 = 2 * lane + 1;
    half2_t w2r[50];
#pragma unroll
    for (int c = 0; c < 25; ++c) {
        float a00 = 0.f, a10 = 0.f, a01 = 0.f, a11 = 0.f;
        if (hAct) {
            int k0 = 50 * w + 2 * c, k1 = k0 + 1;
            a00 = W2[k0 * MDIM + j0]; a10 = W2[k1 * MDIM + j0];
            a01 = W2[k0 * MDIM + j1]; a11 = W2[k1 * MDIM + j1];
        }
        w2r[2 * c]     = pk2(a00, a10);
        w2r[2 * c + 1] = pk2(a01, a11);
    }

    float kap0 = 0.f, kap1 = 0.f, cm0 = 0.f, cm1 = 0.f, b20 = 0.f, b21 = 0.f;
    if (hAct) {
        kap0 = kap_s[j0]; kap1 = kap_s[j1];
        cm0 = cm_s[j0];   cm1 = cm_s[j1];
        b20 = b2[j0];     b21 = b2[j1];
    }

    const unsigned short* Zb = Z + (size_t)b * TSTEPS * HDIM;
    float* outb = out + (size_t)b * TSTEPS * 10;

    float u = 0.f, m0 = 0.f, m1 = 0.f;
    unsigned short zA = 0, zB = 0;          // 2-step-ahead z prefetch
    if (hAct) { zA = Zb[n]; zB = Zb[HDIM + n]; }

    int sm[50];                             // m pairs broadcast (sgpr-resident)
#pragma unroll
    for (int c = 0; c < 50; ++c) sm[c] = 0;

    __syncthreads();

    auto stepf = [&](const int P, unsigned short& zreg, const int st) {
        // ---- unified dot block: h (lanes<50) and y_{st-1} (wave0 lanes 50-59)
        float acc = base_b;
        if (hAct) {
            u = 0.81873075307798182f * u + bf2f(zreg);   // exp(-1/5)
            int stn = st + 2; stn = (stn < TSTEPS) ? stn : TSTEPS - 1;
            zreg = Zb[(size_t)stn * HDIM + n];
            acc += u;
        }
        float r = acc;
        if (hAct || yAct) {
#pragma unroll
            for (int c = 0; c < 50; ++c)
                r = __builtin_amdgcn_fdot2(w1r[c], as_h2((unsigned)sm[c]), r, false);
        }
        if (yAct && st > 0) outb[(size_t)(st - 1) * 10 + o] = r;
        float h = fmaxf(r, 0.f);

        // ---- in-wave h broadcast: pack pairs on even lanes, 25 readlanes
        float ho = __shfl_xor(h, 1);
        unsigned hpk = as_u32(pk2(h, ho));
        int sh[25];
#pragma unroll
        for (int c = 0; c < 25; ++c) sh[c] = __builtin_amdgcn_readlane((int)hpk, 2 * c);

        // ---- mm2 partial: 2 cols x 25 pair-dots over this wave's h range
        if (hAct) {
            float a0 = 0.f, a1 = 0.f;
#pragma unroll
            for (int c = 0; c < 25; ++c) {
                a0 = __builtin_amdgcn_fdot2(w2r[2 * c],     as_h2((unsigned)sh[c]), a0, false);
                a1 = __builtin_amdgcn_fdot2(w2r[2 * c + 1], as_h2((unsigned)sh[c]), a1, false);
            }
            *(float2*)&part[P][w][j0] = make_float2(a0, a1);   // one ds_write_b64
        }
        wg_barrier();

        // ---- combine partials, tanh, m update (redundant in every wave)
        if (hAct) {
            float2 q0 = *(const float2*)&part[P][0][j0];
            float2 q1 = *(const float2*)&part[P][1][j0];
            float2 q2 = *(const float2*)&part[P][2][j0];
            float2 q3 = *(const float2*)&part[P][3][j0];
            float s0 = ((q0.x + q1.x) + (q2.x + q3.x)) + b20;
            float s1 = ((q0.y + q1.y) + (q2.y + q3.y)) + b21;
            float x0 = s0 * (2.f / 3.f), x1 = s1 * (2.f / 3.f);
            float e0 = __expf(2.f * x0), e1 = __expf(2.f * x1);
            float dm0 = 1.7159f * (1.f - 2.f / (e0 + 1.f));
            float dm1 = 1.7159f * (1.f - 2.f / (e1 + 1.f));
            m0 = kap0 * m0 + cm0 * dm0;      // m_t = kap*m_{t-1} + 3(1-kap)*dm
            m1 = kap1 * m1 + cm1 * dm1;
        }
        unsigned mpk = as_u32(pk2(m0, m1));
#pragma unroll
        for (int c = 0; c < 50; ++c) sm[c] = __builtin_amdgcn_readlane((int)mpk, c);
    };

#pragma unroll 1
    for (int st = 0; st < TSTEPS; st += 2) {
        stepf(0, zA, st);
        stepf(1, zB, st + 1);
    }

    // final y (step TSTEPS-1) from the last m broadcast
    if (yAct) {
        float r = base_b;
#pragma unroll
        for (int c = 0; c < 50; ++c)
            r = __builtin_amdgcn_fdot2(w1r[c], as_h2((unsigned)sm[c]), r, false);
        outb[(size_t)(TSTEPS - 1) * 10 + o] = r;
    }
}

extern "C" void kernel_launch(void* const* d_in, const int* in_sizes, int n_in,
                              void* d_out, int out_size, void* d_ws, size_t ws_size,
                              hipStream_t stream) {
    const float* X  = (const float*)d_in[0];
    const float* ws = (const float*)d_in[1];
    const float* W1 = (const float*)d_in[2];
    const float* b1 = (const float*)d_in[3];
    const float* W2 = (const float*)d_in[4];
    const float* b2 = (const float*)d_in[5];
    const float* Wy = (const float*)d_in[6];
    const float* by = (const float*)d_in[7];
    float* out = (float*)d_out;

    unsigned short* wpt = (unsigned short*)d_ws;
    unsigned short* Z   = (unsigned short*)((char*)d_ws + Z_OFF);

    hipLaunchKernelGGL(prep_wpt, dim3((NPAD * KPAD) / 256), dim3(256), 0, stream, ws, W1, wpt);
    hipLaunchKernelGGL(gemm_z, dim3(MT / 128), dim3(256), 0, stream, X, wpt, Z);
    hipLaunchKernelGGL(scan_seq, dim3(BATCH), dim3(256), 0, stream,
                       Z, W1, b1, W2, b2, Wy, by, out);
}

// Round 7
// 1038.041 us; speedup vs baseline: 1.6039x; 1.0018x over previous
//
#include <hip/hip_runtime.h>
#include <math.h>

#define SDIM 1000
#define KPAD 1024
#define HDIM 200
#define MDIM 100
#define NPAD 208
#define TSTEPS 1024
#define BATCH 128
#define MT (BATCH*TSTEPS)
#define TOTX ((size_t)MT*(size_t)SDIM)

// ws layout: [0, 425984) WpT bf16 [208][1024]; [458752, +52428800) Z bf16 [131072][200]
#define Z_OFF 458752

typedef _Float16 half2_t __attribute__((ext_vector_type(2)));
typedef __attribute__((ext_vector_type(8))) short short8;
typedef __attribute__((ext_vector_type(4))) float f32x4;

static __device__ __forceinline__ unsigned short f2bf(float f) {
    unsigned u = __float_as_uint(f);
    unsigned r = 0x7fffu + ((u >> 16) & 1u);   // RNE
    return (unsigned short)((u + r) >> 16);
}
static __device__ __forceinline__ float bf2f(unsigned short h) {
    return __uint_as_float((unsigned)h << 16);
}
static __device__ __forceinline__ half2_t as_h2(unsigned v) {
    union { unsigned u; half2_t h; } c; c.u = v; return c.h;
}
static __device__ __forceinline__ unsigned as_u32(half2_t h) {
    union { half2_t h; unsigned u; } c; c.h = h; return c.u;
}
static __device__ __forceinline__ half2_t pk2(float a, float b) {
    half2_t r; r[0] = (_Float16)a; r[1] = (_Float16)b; return r;
}

// Raw workgroup barrier: drains ONLY lgkm (LDS); global ops stay in flight.
static __device__ __forceinline__ void wg_barrier() {
    asm volatile("s_waitcnt lgkmcnt(0)" ::: "memory");
    __builtin_amdgcn_s_barrier();
    asm volatile("" ::: "memory");
}

// ---------------------------------------------------------------------------
// Kernel 0: WpT[n][k] = relu(w_s[k]) * W1[k][n]  (bf16, transposed, padded)
// ---------------------------------------------------------------------------
__global__ __launch_bounds__(256) void prep_wpt(const float* __restrict__ w_s,
                                                const float* __restrict__ W1,
                                                unsigned short* __restrict__ wpt) {
    int idx = blockIdx.x * 256 + threadIdx.x;   // 208*1024 total
    int n = idx >> 10, k = idx & (KPAD - 1);
    float v = 0.f;
    if (n < HDIM && k < SDIM) {
        float ws = fmaxf(w_s[k], 0.f);
        v = ws * W1[k * HDIM + n];
    }
    wpt[idx] = f2bf(v);
}

// ---------------------------------------------------------------------------
// Kernel 1: Z = bf16(X) @ WpT^T.  BM=128 (4 waves x 2 m-tiles), BN=208, BK=32.
// A and B staged in LDS (double-buffered).  (unchanged)
// ---------------------------------------------------------------------------
__global__ __launch_bounds__(256) void gemm_z(const float* __restrict__ X,
                                              const unsigned short* __restrict__ wpt,
                                              unsigned short* __restrict__ Z) {
    __shared__ __align__(16) unsigned short Abuf[2][128][40];
    __shared__ __align__(16) unsigned short Bbuf[2][13][16][40];
    const int t = threadIdx.x;
    const int m0 = blockIdx.x * 128;
    const int lane = t & 63, w = t >> 6;

    f32x4 acc[2][13];
#pragma unroll
    for (int mt = 0; mt < 2; ++mt)
#pragma unroll
        for (int i = 0; i < 13; ++i) acc[mt][i] = (f32x4){0.f, 0.f, 0.f, 0.f};

    auto stageA = [&](int bsel, int k0) {
        const int row = t >> 1, half = t & 1;
        size_t g = (size_t)(m0 + row) * SDIM + (size_t)(k0 + half * 16);
        float4 f0{}, f1{}, f2{}, f3{};
        if (g + 15 < TOTX) {
            f0 = *(const float4*)(X + g);      f1 = *(const float4*)(X + g + 4);
            f2 = *(const float4*)(X + g + 8);  f3 = *(const float4*)(X + g + 12);
        }
        short8 p0, p1;
        p0[0]=(short)f2bf(f0.x); p0[1]=(short)f2bf(f0.y); p0[2]=(short)f2bf(f0.z); p0[3]=(short)f2bf(f0.w);
        p0[4]=(short)f2bf(f1.x); p0[5]=(short)f2bf(f1.y); p0[6]=(short)f2bf(f1.z); p0[7]=(short)f2bf(f1.w);
        p1[0]=(short)f2bf(f2.x); p1[1]=(short)f2bf(f2.y); p1[2]=(short)f2bf(f2.z); p1[3]=(short)f2bf(f2.w);
        p1[4]=(short)f2bf(f3.x); p1[5]=(short)f2bf(f3.y); p1[6]=(short)f2bf(f3.z); p1[7]=(short)f2bf(f3.w);
        *(short8*)&Abuf[bsel][row][half * 16]     = p0;
        *(short8*)&Abuf[bsel][row][half * 16 + 8] = p1;
    };
    auto stageB = [&](int bsel, int k0) {
#pragma unroll
        for (int j = 0; j < 4; ++j) {
            int e = t + 256 * j;
            if (e < 832) {
                int n = e >> 2, q = e & 3;
                short8 v = *(const short8*)(wpt + (size_t)n * KPAD + k0 + q * 8);
                *(short8*)&Bbuf[bsel][n >> 4][n & 15][q * 8] = v;
            }
        }
    };

    stageA(0, 0);
    stageB(0, 0);
#pragma unroll 1
    for (int it = 0; it < 32; ++it) {
        __syncthreads();
        if (it + 1 < 32) { stageA((it + 1) & 1, (it + 1) * 32); stageB((it + 1) & 1, (it + 1) * 32); }
        const int bsel = it & 1;
        const short8 av0 = *(const short8*)&Abuf[bsel][w * 32 + (lane & 15)][(lane >> 4) * 8];
        const short8 av1 = *(const short8*)&Abuf[bsel][w * 32 + 16 + (lane & 15)][(lane >> 4) * 8];
#pragma unroll
        for (int nt = 0; nt < 13; ++nt) {
            const short8 bv = *(const short8*)&Bbuf[bsel][nt][lane & 15][(lane >> 4) * 8];
            acc[0][nt] = __builtin_amdgcn_mfma_f32_16x16x32_bf16(av0, bv, acc[0][nt], 0, 0, 0);
            acc[1][nt] = __builtin_amdgcn_mfma_f32_16x16x32_bf16(av1, bv, acc[1][nt], 0, 0, 0);
        }
    }

    const int colb = lane & 15;
#pragma unroll
    for (int mt = 0; mt < 2; ++mt) {
        const int rowb = m0 + w * 32 + mt * 16 + (lane >> 4) * 4;
#pragma unroll
        for (int nt = 0; nt < 13; ++nt) {
            int col = nt * 16 + colb;
            if (col < HDIM) {
#pragma unroll
                for (int r = 0; r < 4; ++r)
                    Z[(size_t)(rowb + r) * HDIM + col] = f2bf(acc[mt][nt][r]);
            }
        }
    }
}

// ---------------------------------------------------------------------------
// Kernel 2: sequential scan, 1 WG (256 thr) per batch element.
// ONE barrier per step; broadcasts via v_readlane->SGPR, never LDS.
//  - h ownership: wave w, lane i<50 owns h[50w+i]; u,z in-lane.
//  - mm1: h = relu(u + b1 + sum_k m_k * (kap_k*W1b[k][n]))  (kappa folded in W1)
//    y-cols (wave0 lanes 50-59) share the same dot block with Wy weights.
//  - h broadcast in-wave: shfl_xor(1) pack -> 25 readlanes -> sgpr.
//  - mm2 k-split by wave: wave w accumulates partial a2[j] over its 50 h's
//    for 2 cols/lane; one ds_write_b64 of partials; barrier.
//  - every lane reads 4 partials/col, sums, tanh, updates m[2l],m[2l+1]
//    redundantly in all waves; 50 readlanes publish m pairs to sgpr.
// ---------------------------------------------------------------------------
__global__ __launch_bounds__(256, 1) void scan_seq(const unsigned short* __restrict__ Z,
        const float* __restrict__ W1, const float* __restrict__ b1,
        const float* __restrict__ W2, const float* __restrict__ b2,
        const float* __restrict__ Wy, const float* __restrict__ by,
        float* __restrict__ out) {
    __shared__ __align__(16) float part[2][4][104];   // [buf][wave][col] partial a2
    __shared__ float kap_s[104], cm_s[104];

    const int t = threadIdx.x;
    const int b = blockIdx.x;
    const int w = t >> 6, lane = t & 63;
    const int n = 50 * w + lane;            // owned h column (lane<50)
    const bool hAct = lane < 50;
    const bool yAct = (w == 0) && (lane >= 50 && lane < 60);
    const int o = lane - 50;

    if (t < 104) {
        float kv = 0.f, cv = 0.f;
        if (t < MDIM) {                     // kappa_m in fp64 to match numpy
            double lg = 1.0000000434294482
                      + (double)t * ((2.9999999995657055 - 1.0000000434294482) / 99.0);
            double tau = exp(lg * 2.302585092994046);
            kv = (float)exp(-1.0 / tau);
            cv = 3.0f * (1.0f - kv);
        }
        kap_s[t] = kv; cm_s[t] = cv;
    }
    __syncthreads();

    // mm1 / y weights (shared dot block): 50 half2 pairs over k=0..99 (m-index)
    half2_t w1r[50];
#pragma unroll
    for (int c = 0; c < 50; ++c) {
        float a0 = 0.f, a1 = 0.f;
        if (hAct) {
            a0 = kap_s[2 * c]     * W1[(SDIM + 2 * c)     * HDIM + n];
            a1 = kap_s[2 * c + 1] * W1[(SDIM + 2 * c + 1) * HDIM + n];
        } else if (yAct) {
            a0 = Wy[(2 * c) * 10 + o];
            a1 = Wy[(2 * c + 1) * 10 + o];
        }
        w1r[c] = pk2(a0, a1);
    }
    float base_b = hAct ? b1[n] : (yAct ? by[o] : 0.f);

    // mm2 partial weights: wave w's k-range [50w, 50w+50), cols j0=2*lane, j1=2*lane+1
    const int j0 = 2 * lane, j1 = 2 * lane + 1;
    half2_t w2r[50];
#pragma unroll
    for (int c = 0; c < 25; ++c) {
        float a00 = 0.f, a10 = 0.f, a01 = 0.f, a11 = 0.f;
        if (hAct) {
            int k0 = 50 * w + 2 * c, k1 = k0 + 1;
            a00 = W2[k0 * MDIM + j0]; a10 = W2[k1 * MDIM + j0];
            a01 = W2[k0 * MDIM + j1]; a11 = W2[k1 * MDIM + j1];
        }
        w2r[2 * c]     = pk2(a00, a10);
        w2r[2 * c + 1] = pk2(a01, a11);
    }

    float kap0 = 0.f, kap1 = 0.f, cm0 = 0.f, cm1 = 0.f, b20 = 0.f, b21 = 0.f;
    if (hAct) {
        kap0 = kap_s[j0]; kap1 = kap_s[j1];
        cm0 = cm_s[j0];   cm1 = cm_s[j1];
        b20 = b2[j0];     b21 = b2[j1];
    }

    const unsigned short* Zb = Z + (size_t)b * TSTEPS * HDIM;
    float* outb = out + (size_t)b * TSTEPS * 10;

    float u = 0.f, m0 = 0.f, m1 = 0.f;
    unsigned short zA = 0, zB = 0;          // 2-step-ahead z prefetch
    if (hAct) { zA = Zb[n]; zB = Zb[HDIM + n]; }

    int sm[50];                             // m pairs broadcast (sgpr-resident)
#pragma unroll
    for (int c = 0; c < 50; ++c) sm[c] = 0;

    __syncthreads();

    auto stepf = [&](const int P, unsigned short& zreg, const int st) {
        // ---- unified dot block: h (lanes<50) and y_{st-1} (wave0 lanes 50-59)
        float acc = base_b;
        if (hAct) {
            u = 0.81873075307798182f * u + bf2f(zreg);   // exp(-1/5)
            int stn = st + 2; stn = (stn < TSTEPS) ? stn : TSTEPS - 1;
            zreg = Zb[(size_t)stn * HDIM + n];
            acc += u;
        }
        float r = acc;
        if (hAct || yAct) {
#pragma unroll
            for (int c = 0; c < 50; ++c)
                r = __builtin_amdgcn_fdot2(w1r[c], as_h2((unsigned)sm[c]), r, false);
        }
        if (yAct && st > 0) outb[(size_t)(st - 1) * 10 + o] = r;
        float h = fmaxf(r, 0.f);

        // ---- in-wave h broadcast: pack pairs on even lanes, 25 readlanes
        float ho = __shfl_xor(h, 1);
        unsigned hpk = as_u32(pk2(h, ho));
        int sh[25];
#pragma unroll
        for (int c = 0; c < 25; ++c) sh[c] = __builtin_amdgcn_readlane((int)hpk, 2 * c);

        // ---- mm2 partial: 2 cols x 25 pair-dots over this wave's h range
        if (hAct) {
            float a0 = 0.f, a1 = 0.f;
#pragma unroll
            for (int c = 0; c < 25; ++c) {
                a0 = __builtin_amdgcn_fdot2(w2r[2 * c],     as_h2((unsigned)sh[c]), a0, false);
                a1 = __builtin_amdgcn_fdot2(w2r[2 * c + 1], as_h2((unsigned)sh[c]), a1, false);
            }
            *(float2*)&part[P][w][j0] = make_float2(a0, a1);   // one ds_write_b64
        }
        wg_barrier();

        // ---- combine partials, tanh, m update (redundant in every wave)
        if (hAct) {
            float2 q0 = *(const float2*)&part[P][0][j0];
            float2 q1 = *(const float2*)&part[P][1][j0];
            float2 q2 = *(const float2*)&part[P][2][j0];
            float2 q3 = *(const float2*)&part[P][3][j0];
            float s0 = ((q0.x + q1.x) + (q2.x + q3.x)) + b20;
            float s1 = ((q0.y + q1.y) + (q2.y + q3.y)) + b21;
            float x0 = s0 * (2.f / 3.f), x1 = s1 * (2.f / 3.f);
            float e0 = __expf(2.f * x0), e1 = __expf(2.f * x1);
            float dm0 = 1.7159f * (1.f - 2.f / (e0 + 1.f));
            float dm1 = 1.7159f * (1.f - 2.f / (e1 + 1.f));
            m0 = kap0 * m0 + cm0 * dm0;      // m_t = kap*m_{t-1} + 3(1-kap)*dm
            m1 = kap1 * m1 + cm1 * dm1;
        }
        unsigned mpk = as_u32(pk2(m0, m1));
#pragma unroll
        for (int c = 0; c < 50; ++c) sm[c] = __builtin_amdgcn_readlane((int)mpk, c);
    };

#pragma unroll 1
    for (int st = 0; st < TSTEPS; st += 2) {
        stepf(0, zA, st);
        stepf(1, zB, st + 1);
    }

    // final y (step TSTEPS-1) from the last m broadcast
    if (yAct) {
        float r = base_b;
#pragma unroll
        for (int c = 0; c < 50; ++c)
            r = __builtin_amdgcn_fdot2(w1r[c], as_h2((unsigned)sm[c]), r, false);
        outb[(size_t)(TSTEPS - 1) * 10 + o] = r;
    }
}

extern "C" void kernel_launch(void* const* d_in, const int* in_sizes, int n_in,
                              void* d_out, int out_size, void* d_ws, size_t ws_size,
                              hipStream_t stream) {
    const float* X  = (const float*)d_in[0];
    const float* ws = (const float*)d_in[1];
    const float* W1 = (const float*)d_in[2];
    const float* b1 = (const float*)d_in[3];
    const float* W2 = (const float*)d_in[4];
    const float* b2 = (const float*)d_in[5];
    const float* Wy = (const float*)d_in[6];
    const float* by = (const float*)d_in[7];
    float* out = (float*)d_out;

    unsigned short* wpt = (unsigned short*)d_ws;
    unsigned short* Z   = (unsigned short*)((char*)d_ws + Z_OFF);

    hipLaunchKernelGGL(prep_wpt, dim3((NPAD * KPAD) / 256), dim3(256), 0, stream, ws, W1, wpt);
    hipLaunchKernelGGL(gemm_z, dim3(MT / 128), dim3(256), 0, stream, X, wpt, Z);
    hipLaunchKernelGGL(scan_seq, dim3(BATCH), dim3(256), 0, stream,
                       Z, W1, b1, W2, b2, Wy, by, out);
}

// Round 8
// 1036.334 us; speedup vs baseline: 1.6065x; 1.0016x over previous
//
#include <hip/hip_runtime.h>
#include <math.h>

#define SDIM 1000
#define KPAD 1024
#define HDIM 200
#define MDIM 100
#define NPAD 208
#define TSTEPS 1024
#define BATCH 128
#define MT (BATCH*TSTEPS)
#define TOTX ((size_t)MT*(size_t)SDIM)

// ws layout: [0, 425984) WpT bf16 [208][1024]; [458752, +52428800) Z bf16 [131072][200]
#define Z_OFF 458752

typedef _Float16 half2_t __attribute__((ext_vector_type(2)));
typedef __attribute__((ext_vector_type(8))) short short8;
typedef __attribute__((ext_vector_type(4))) float f32x4;

static __device__ __forceinline__ unsigned short f2bf(float f) {
    unsigned u = __float_as_uint(f);
    unsigned r = 0x7fffu + ((u >> 16) & 1u);   // RNE
    return (unsigned short)((u + r) >> 16);
}
static __device__ __forceinline__ float bf2f(unsigned short h) {
    return __uint_as_float((unsigned)h << 16);
}
static __device__ __forceinline__ half2_t as_h2(unsigned v) {
    union { unsigned u; half2_t h; } c; c.u = v; return c.h;
}
static __device__ __forceinline__ unsigned as_u32(half2_t h) {
    union { half2_t h; unsigned u; } c; c.h = h; return c.u;
}
static __device__ __forceinline__ half2_t pk2(float a, float b) {
    half2_t r; r[0] = (_Float16)a; r[1] = (_Float16)b; return r;
}

// Raw workgroup barrier: drains ONLY lgkm (LDS); global ops stay in flight.
static __device__ __forceinline__ void wg_barrier() {
    asm volatile("s_waitcnt lgkmcnt(0)" ::: "memory");
    __builtin_amdgcn_s_barrier();
    asm volatile("" ::: "memory");
}

// ---------------------------------------------------------------------------
// Kernel 0: WpT[n][k] = relu(w_s[k]) * W1[k][n]  (bf16, transposed, padded)
// ---------------------------------------------------------------------------
__global__ __launch_bounds__(256) void prep_wpt(const float* __restrict__ w_s,
                                                const float* __restrict__ W1,
                                                unsigned short* __restrict__ wpt) {
    int idx = blockIdx.x * 256 + threadIdx.x;   // 208*1024 total
    int n = idx >> 10, k = idx & (KPAD - 1);
    float v = 0.f;
    if (n < HDIM && k < SDIM) {
        float ws = fmaxf(w_s[k], 0.f);
        v = ws * W1[k * HDIM + n];
    }
    wpt[idx] = f2bf(v);
}

// ---------------------------------------------------------------------------
// Kernel 1: Z = bf16(X) @ WpT^T.  BM=128 (4 waves x 2 m-tiles), BN=208, BK=32.
// A and B staged in LDS (double-buffered).  (unchanged)
// ---------------------------------------------------------------------------
__global__ __launch_bounds__(256) void gemm_z(const float* __restrict__ X,
                                              const unsigned short* __restrict__ wpt,
                                              unsigned short* __restrict__ Z) {
    __shared__ __align__(16) unsigned short Abuf[2][128][40];
    __shared__ __align__(16) unsigned short Bbuf[2][13][16][40];
    const int t = threadIdx.x;
    const int m0 = blockIdx.x * 128;
    const int lane = t & 63, w = t >> 6;

    f32x4 acc[2][13];
#pragma unroll
    for (int mt = 0; mt < 2; ++mt)
#pragma unroll
        for (int i = 0; i < 13; ++i) acc[mt][i] = (f32x4){0.f, 0.f, 0.f, 0.f};

    auto stageA = [&](int bsel, int k0) {
        const int row = t >> 1, half = t & 1;
        size_t g = (size_t)(m0 + row) * SDIM + (size_t)(k0 + half * 16);
        float4 f0{}, f1{}, f2{}, f3{};
        if (g + 15 < TOTX) {
            f0 = *(const float4*)(X + g);      f1 = *(const float4*)(X + g + 4);
            f2 = *(const float4*)(X + g + 8);  f3 = *(const float4*)(X + g + 12);
        }
        short8 p0, p1;
        p0[0]=(short)f2bf(f0.x); p0[1]=(short)f2bf(f0.y); p0[2]=(short)f2bf(f0.z); p0[3]=(short)f2bf(f0.w);
        p0[4]=(short)f2bf(f1.x); p0[5]=(short)f2bf(f1.y); p0[6]=(short)f2bf(f1.z); p0[7]=(short)f2bf(f1.w);
        p1[0]=(short)f2bf(f2.x); p1[1]=(short)f2bf(f2.y); p1[2]=(short)f2bf(f2.z); p1[3]=(short)f2bf(f2.w);
        p1[4]=(short)f2bf(f3.x); p1[5]=(short)f2bf(f3.y); p1[6]=(short)f2bf(f3.z); p1[7]=(short)f2bf(f3.w);
        *(short8*)&Abuf[bsel][row][half * 16]     = p0;
        *(short8*)&Abuf[bsel][row][half * 16 + 8] = p1;
    };
    auto stageB = [&](int bsel, int k0) {
#pragma unroll
        for (int j = 0; j < 4; ++j) {
            int e = t + 256 * j;
            if (e < 832) {
                int n = e >> 2, q = e & 3;
                short8 v = *(const short8*)(wpt + (size_t)n * KPAD + k0 + q * 8);
                *(short8*)&Bbuf[bsel][n >> 4][n & 15][q * 8] = v;
            }
        }
    };

    stageA(0, 0);
    stageB(0, 0);
#pragma unroll 1
    for (int it = 0; it < 32; ++it) {
        __syncthreads();
        if (it + 1 < 32) { stageA((it + 1) & 1, (it + 1) * 32); stageB((it + 1) & 1, (it + 1) * 32); }
        const int bsel = it & 1;
        const short8 av0 = *(const short8*)&Abuf[bsel][w * 32 + (lane & 15)][(lane >> 4) * 8];
        const short8 av1 = *(const short8*)&Abuf[bsel][w * 32 + 16 + (lane & 15)][(lane >> 4) * 8];
#pragma unroll
        for (int nt = 0; nt < 13; ++nt) {
            const short8 bv = *(const short8*)&Bbuf[bsel][nt][lane & 15][(lane >> 4) * 8];
            acc[0][nt] = __builtin_amdgcn_mfma_f32_16x16x32_bf16(av0, bv, acc[0][nt], 0, 0, 0);
            acc[1][nt] = __builtin_amdgcn_mfma_f32_16x16x32_bf16(av1, bv, acc[1][nt], 0, 0, 0);
        }
    }

    const int colb = lane & 15;
#pragma unroll
    for (int mt = 0; mt < 2; ++mt) {
        const int rowb = m0 + w * 32 + mt * 16 + (lane >> 4) * 4;
#pragma unroll
        for (int nt = 0; nt < 13; ++nt) {
            int col = nt * 16 + colb;
            if (col < HDIM) {
#pragma unroll
                for (int r = 0; r < 4; ++r)
                    Z[(size_t)(rowb + r) * HDIM + col] = f2bf(acc[mt][nt][r]);
            }
        }
    }
}

// ---------------------------------------------------------------------------
// Kernel 2: sequential scan, 1 WG (256 thr) per batch element.
// ONE barrier per step; broadcasts via v_readlane->SGPR, never LDS.
//  - h ownership: wave w, lane i<50 owns h[50w+i]; u,z in-lane.
//  - mm1: h = relu(u + b1 + sum_k m_k * (kap_k*W1b[k][n]))  (kappa folded in W1)
//    y-cols (wave0 lanes 50-59) share the same dot block with Wy weights.
//  - h broadcast in-wave: shfl_xor(1) pack -> 25 readlanes -> sgpr.
//  - mm2 k-split by wave: wave w accumulates partial a2[j] over its 50 h's
//    for 2 cols/lane; one ds_write_b64 of partials; barrier.
//  - every lane reads 4 partials/col, sums, tanh, updates m[2l],m[2l+1]
//    redundantly in all waves; 50 readlanes publish m pairs to sgpr.
// ---------------------------------------------------------------------------
__global__ __launch_bounds__(256, 1) void scan_seq(const unsigned short* __restrict__ Z,
        const float* __restrict__ W1, const float* __restrict__ b1,
        const float* __restrict__ W2, const float* __restrict__ b2,
        const float* __restrict__ Wy, const float* __restrict__ by,
        float* __restrict__ out) {
    __shared__ __align__(16) float part[2][4][104];   // [buf][wave][col] partial a2
    __shared__ float kap_s[104], cm_s[104];

    const int t = threadIdx.x;
    const int b = blockIdx.x;
    const int w = t >> 6, lane = t & 63;
    const int n = 50 * w + lane;            // owned h column (lane<50)
    const bool hAct = lane < 50;
    const bool yAct = (w == 0) && (lane >= 50 && lane < 60);
    const int o = lane - 50;

    if (t < 104) {
        float kv = 0.f, cv = 0.f;
        if (t < MDIM) {                     // kappa_m in fp64 to match numpy
            double lg = 1.0000000434294482
                      + (double)t * ((2.9999999995657055 - 1.0000000434294482) / 99.0);
            double tau = exp(lg * 2.302585092994046);
            kv = (float)exp(-1.0 / tau);
            cv = 3.0f * (1.0f - kv);
        }
        kap_s[t] = kv; cm_s[t] = cv;
    }
    __syncthreads();

    // mm1 / y weights (shared dot block): 50 half2 pairs over k=0..99 (m-index)
    half2_t w1r[50];
#pragma unroll
    for (int c = 0; c < 50; ++c) {
        float a0 = 0.f, a1 = 0.f;
        if (hAct) {
            a0 = kap_s[2 * c]     * W1[(SDIM + 2 * c)     * HDIM + n];
            a1 = kap_s[2 * c + 1] * W1[(SDIM + 2 * c + 1) * HDIM + n];
        } else if (yAct) {
            a0 = Wy[(2 * c) * 10 + o];
            a1 = Wy[(2 * c + 1) * 10 + o];
        }
        w1r[c] = pk2(a0, a1);
    }
    float base_b = hAct ? b1[n] : (yAct ? by[o] : 0.f);

    // mm2 partial weights: wave w's k-range [50w, 50w+50), cols j0=2*lane, j1=2*lane+1
    const int j0 = 2 * lane, j1 = 2 * lane + 1;
    half2_t w2r[50];
#pragma unroll
    for (int c = 0; c < 25; ++c) {
        float a00 = 0.f, a10 = 0.f, a01 = 0.f, a11 = 0.f;
        if (hAct) {
            int k0 = 50 * w + 2 * c, k1 = k0 + 1;
            a00 = W2[k0 * MDIM + j0]; a10 = W2[k1 * MDIM + j0];
            a01 = W2[k0 * MDIM + j1]; a11 = W2[k1 * MDIM + j1];
        }
        w2r[2 * c]     = pk2(a00, a10);
        w2r[2 * c + 1] = pk2(a01, a11);
    }

    float kap0 = 0.f, kap1 = 0.f, cm0 = 0.f, cm1 = 0.f, b20 = 0.f, b21 = 0.f;
    if (hAct) {
        kap0 = kap_s[j0]; kap1 = kap_s[j1];
        cm0 = cm_s[j0];   cm1 = cm_s[j1];
        b20 = b2[j0];     b21 = b2[j1];
    }

    const unsigned short* Zb = Z + (size_t)b * TSTEPS * HDIM;
    float* outb = out + (size_t)b * TSTEPS * 10;

    float u = 0.f, m0 = 0.f, m1 = 0.f;
    unsigned short zA = 0, zB = 0;          // 2-step-ahead z prefetch
    if (hAct) { zA = Zb[n]; zB = Zb[HDIM + n]; }

    int sm[50];                             // m pairs broadcast (sgpr-resident)
#pragma unroll
    for (int c = 0; c < 50; ++c) sm[c] = 0;

    __syncthreads();

    auto stepf = [&](const int P, unsigned short& zreg, const int st) {
        // ---- unified dot block: h (lanes<50) and y_{st-1} (wave0 lanes 50-59)
        float acc = base_b;
        if (hAct) {
            u = 0.81873075307798182f * u + bf2f(zreg);   // exp(-1/5)
            int stn = st + 2; stn = (stn < TSTEPS) ? stn : TSTEPS - 1;
            zreg = Zb[(size_t)stn * HDIM + n];
            acc += u;
        }
        float r = acc;
        if (hAct || yAct) {
#pragma unroll
            for (int c = 0; c < 50; ++c)
                r = __builtin_amdgcn_fdot2(w1r[c], as_h2((unsigned)sm[c]), r, false);
        }
        if (yAct && st > 0) outb[(size_t)(st - 1) * 10 + o] = r;
        float h = fmaxf(r, 0.f);

        // ---- in-wave h broadcast: pack pairs on even lanes, 25 readlanes
        float ho = __shfl_xor(h, 1);
        unsigned hpk = as_u32(pk2(h, ho));
        int sh[25];
#pragma unroll
        for (int c = 0; c < 25; ++c) sh[c] = __builtin_amdgcn_readlane((int)hpk, 2 * c);

        // ---- mm2 partial: 2 cols x 25 pair-dots over this wave's h range
        if (hAct) {
            float a0 = 0.f, a1 = 0.f;
#pragma unroll
            for (int c = 0; c < 25; ++c) {
                a0 = __builtin_amdgcn_fdot2(w2r[2 * c],     as_h2((unsigned)sh[c]), a0, false);
                a1 = __builtin_amdgcn_fdot2(w2r[2 * c + 1], as_h2((unsigned)sh[c]), a1, false);
            }
            *(float2*)&part[P][w][j0] = make_float2(a0, a1);   // one ds_write_b64
        }
        wg_barrier();

        // ---- combine partials, tanh, m update (redundant in every wave)
        if (hAct) {
            float2 q0 = *(const float2*)&part[P][0][j0];
            float2 q1 = *(const float2*)&part[P][1][j0];
            float2 q2 = *(const float2*)&part[P][2][j0];
            float2 q3 = *(const float2*)&part[P][3][j0];
            float s0 = ((q0.x + q1.x) + (q2.x + q3.x)) + b20;
            float s1 = ((q0.y + q1.y) + (q2.y + q3.y)) + b21;
            float x0 = s0 * (2.f / 3.f), x1 = s1 * (2.f / 3.f);
            float e0 = __expf(2.f * x0), e1 = __expf(2.f * x1);
            float dm0 = 1.7159f * (1.f - 2.f / (e0 + 1.f));
            float dm1 = 1.7159f * (1.f - 2.f / (e1 + 1.f));
            m0 = kap0 * m0 + cm0 * dm0;      // m_t = kap*m_{t-1} + 3(1-kap)*dm
            m1 = kap1 * m1 + cm1 * dm1;
        }
        unsigned mpk = as_u32(pk2(m0, m1));
#pragma unroll
        for (int c = 0; c < 50; ++c) sm[c] = __builtin_amdgcn_readlane((int)mpk, c);
    };

#pragma unroll 1
    for (int st = 0; st < TSTEPS; st += 2) {
        stepf(0, zA, st);
        stepf(1, zB, st + 1);
    }

    // final y (step TSTEPS-1) from the last m broadcast
    if (yAct) {
        float r = base_b;
#pragma unroll
        for (int c = 0; c < 50; ++c)
            r = __builtin_amdgcn_fdot2(w1r[c], as_h2((unsigned)sm[c]), r, false);
        outb[(size_t)(TSTEPS - 1) * 10 + o] = r;
    }
}

extern "C" void kernel_launch(void* const* d_in, const int* in_sizes, int n_in,
                              void* d_out, int out_size, void* d_ws, size_t ws_size,
                              hipStream_t stream) {
    const float* X  = (const float*)d_in[0];
    const float* ws = (const float*)d_in[1];
    const float* W1 = (const float*)d_in[2];
    const float* b1 = (const float*)d_in[3];
    const float* W2 = (const float*)d_in[4];
    const float* b2 = (const float*)d_in[5];
    const float* Wy = (const float*)d_in[6];
    const float* by = (const float*)d_in[7];
    float* out = (float*)d_out;

    unsigned short* wpt = (unsigned short*)d_ws;
    unsigned short* Z   = (unsigned short*)((char*)d_ws + Z_OFF);

    hipLaunchKernelGGL(prep_wpt, dim3((NPAD * KPAD) / 256), dim3(256), 0, stream, ws, W1, wpt);
    hipLaunchKernelGGL(gemm_z, dim3(MT / 128), dim3(256), 0, stream, X, wpt, Z);
    hipLaunchKernelGGL(scan_seq, dim3(BATCH), dim3(256), 0, stream,
                       Z, W1, b1, W2, b2, Wy, by, out);
}

// Round 10
// 976.908 us; speedup vs baseline: 1.7042x; 1.0608x over previous
//
#include <hip/hip_runtime.h>
#include <math.h>

#define SDIM 1000
#define KPAD 1024
#define HDIM 200
#define MDIM 100
#define NPAD 208
#define TSTEPS 1024
#define BATCH 128
#define MT (BATCH*TSTEPS)
#define TOTX ((size_t)MT*(size_t)SDIM)

// ws layout: [0, 425984) WpT bf16 [208][1024]; [458752, +52428800) Z bf16 [131072][200]
#define Z_OFF 458752

typedef _Float16 half2_t __attribute__((ext_vector_type(2)));
typedef __attribute__((ext_vector_type(8))) short short8;
typedef __attribute__((ext_vector_type(4))) float f32x4;

static __device__ __forceinline__ unsigned short f2bf(float f) {
    unsigned u = __float_as_uint(f);
    unsigned r = 0x7fffu + ((u >> 16) & 1u);   // RNE
    return (unsigned short)((u + r) >> 16);
}
static __device__ __forceinline__ float bf2f(unsigned short h) {
    return __uint_as_float((unsigned)h << 16);
}
static __device__ __forceinline__ half2_t as_h2(unsigned v) {
    union { unsigned u; half2_t h; } c; c.u = v; return c.h;
}
static __device__ __forceinline__ unsigned as_u32(half2_t h) {
    union { half2_t h; unsigned u; } c; c.h = h; return c.u;
}
static __device__ __forceinline__ half2_t pk2(float a, float b) {
    half2_t r; r[0] = (_Float16)a; r[1] = (_Float16)b; return r;
}

// Raw workgroup barrier: drains ONLY lgkm (LDS); global ops stay in flight.
static __device__ __forceinline__ void wg_barrier() {
    asm volatile("s_waitcnt lgkmcnt(0)" ::: "memory");
    __builtin_amdgcn_s_barrier();
    asm volatile("" ::: "memory");
}

// ---------------------------------------------------------------------------
// Kernel 0: WpT[n][k] = relu(w_s[k]) * W1[k][n]  (bf16, transposed, padded)
// ---------------------------------------------------------------------------
__global__ __launch_bounds__(256) void prep_wpt(const float* __restrict__ w_s,
                                                const float* __restrict__ W1,
                                                unsigned short* __restrict__ wpt) {
    int idx = blockIdx.x * 256 + threadIdx.x;   // 208*1024 total
    int n = idx >> 10, k = idx & (KPAD - 1);
    float v = 0.f;
    if (n < HDIM && k < SDIM) {
        float ws = fmaxf(w_s[k], 0.f);
        v = ws * W1[k * HDIM + n];
    }
    wpt[idx] = f2bf(v);
}

// ---------------------------------------------------------------------------
// Kernel 1: Z = bf16(X) @ WpT^T.  BM=128 (4 waves x 2 m-tiles), BN=208, BK=32.
// A and B staged in LDS (double-buffered).  (unchanged)
// ---------------------------------------------------------------------------
__global__ __launch_bounds__(256) void gemm_z(const float* __restrict__ X,
                                              const unsigned short* __restrict__ wpt,
                                              unsigned short* __restrict__ Z) {
    __shared__ __align__(16) unsigned short Abuf[2][128][40];
    __shared__ __align__(16) unsigned short Bbuf[2][13][16][40];
    const int t = threadIdx.x;
    const int m0 = blockIdx.x * 128;
    const int lane = t & 63, w = t >> 6;

    f32x4 acc[2][13];
#pragma unroll
    for (int mt = 0; mt < 2; ++mt)
#pragma unroll
        for (int i = 0; i < 13; ++i) acc[mt][i] = (f32x4){0.f, 0.f, 0.f, 0.f};

    auto stageA = [&](int bsel, int k0) {
        const int row = t >> 1, half = t & 1;
        size_t g = (size_t)(m0 + row) * SDIM + (size_t)(k0 + half * 16);
        float4 f0{}, f1{}, f2{}, f3{};
        if (g + 15 < TOTX) {
            f0 = *(const float4*)(X + g);      f1 = *(const float4*)(X + g + 4);
            f2 = *(const float4*)(X + g + 8);  f3 = *(const float4*)(X + g + 12);
        }
        short8 p0, p1;
        p0[0]=(short)f2bf(f0.x); p0[1]=(short)f2bf(f0.y); p0[2]=(short)f2bf(f0.z); p0[3]=(short)f2bf(f0.w);
        p0[4]=(short)f2bf(f1.x); p0[5]=(short)f2bf(f1.y); p0[6]=(short)f2bf(f1.z); p0[7]=(short)f2bf(f1.w);
        p1[0]=(short)f2bf(f2.x); p1[1]=(short)f2bf(f2.y); p1[2]=(short)f2bf(f2.z); p1[3]=(short)f2bf(f2.w);
        p1[4]=(short)f2bf(f3.x); p1[5]=(short)f2bf(f3.y); p1[6]=(short)f2bf(f3.z); p1[7]=(short)f2bf(f3.w);
        *(short8*)&Abuf[bsel][row][half * 16]     = p0;
        *(short8*)&Abuf[bsel][row][half * 16 + 8] = p1;
    };
    auto stageB = [&](int bsel, int k0) {
#pragma unroll
        for (int j = 0; j < 4; ++j) {
            int e = t + 256 * j;
            if (e < 832) {
                int n = e >> 2, q = e & 3;
                short8 v = *(const short8*)(wpt + (size_t)n * KPAD + k0 + q * 8);
                *(short8*)&Bbuf[bsel][n >> 4][n & 15][q * 8] = v;
            }
        }
    };

    stageA(0, 0);
    stageB(0, 0);
#pragma unroll 1
    for (int it = 0; it < 32; ++it) {
        __syncthreads();
        if (it + 1 < 32) { stageA((it + 1) & 1, (it + 1) * 32); stageB((it + 1) & 1, (it + 1) * 32); }
        const int bsel = it & 1;
        const short8 av0 = *(const short8*)&Abuf[bsel][w * 32 + (lane & 15)][(lane >> 4) * 8];
        const short8 av1 = *(const short8*)&Abuf[bsel][w * 32 + 16 + (lane & 15)][(lane >> 4) * 8];
#pragma unroll
        for (int nt = 0; nt < 13; ++nt) {
            const short8 bv = *(const short8*)&Bbuf[bsel][nt][lane & 15][(lane >> 4) * 8];
            acc[0][nt] = __builtin_amdgcn_mfma_f32_16x16x32_bf16(av0, bv, acc[0][nt], 0, 0, 0);
            acc[1][nt] = __builtin_amdgcn_mfma_f32_16x16x32_bf16(av1, bv, acc[1][nt], 0, 0, 0);
        }
    }

    const int colb = lane & 15;
#pragma unroll
    for (int mt = 0; mt < 2; ++mt) {
        const int rowb = m0 + w * 32 + mt * 16 + (lane >> 4) * 4;
#pragma unroll
        for (int nt = 0; nt < 13; ++nt) {
            int col = nt * 16 + colb;
            if (col < HDIM) {
#pragma unroll
                for (int r = 0; r < 4; ++r)
                    Z[(size_t)(rowb + r) * HDIM + col] = f2bf(acc[mt][nt][r]);
            }
        }
    }
}

// ---------------------------------------------------------------------------
// Kernel 2: sequential scan, 1 WG (256 thr) per batch element.
// One barrier/step; readlane->SGPR broadcasts; 4-way ILP in both dot blocks;
// tanh via exp2+rcp (no IEEE divide on the critical tail).
// ---------------------------------------------------------------------------
#define KEXP 1.9235933878519513f   /* (4/3)*log2(e): e^{2x} = 2^{(s+b2)*KEXP} */

__global__ __launch_bounds__(256, 1) void scan_seq(const unsigned short* __restrict__ Z,
        const float* __restrict__ W1, const float* __restrict__ b1,
        const float* __restrict__ W2, const float* __restrict__ b2,
        const float* __restrict__ Wy, const float* __restrict__ by,
        float* __restrict__ out) {
    __shared__ __align__(16) float part[2][4][104];   // [buf][wave][col] partial a2
    __shared__ float kap_s[104], cm_s[104];

    const int t = threadIdx.x;
    const int b = blockIdx.x;
    const int w = t >> 6, lane = t & 63;
    const int n = 50 * w + lane;            // owned h column (lane<50)
    const bool hAct = lane < 50;
    const bool yAct = (w == 0) && (lane >= 50 && lane < 60);
    const int o = lane - 50;

    if (t < 104) {
        float kv = 0.f, cv = 0.f;
        if (t < MDIM) {                     // kappa_m in fp64 to match numpy
            double lg = 1.0000000434294482
                      + (double)t * ((2.9999999995657055 - 1.0000000434294482) / 99.0);
            double tau = exp(lg * 2.302585092994046);
            kv = (float)exp(-1.0 / tau);
            cv = 3.0f * (1.0f - kv);
        }
        kap_s[t] = kv; cm_s[t] = cv;
    }
    __syncthreads();

    // mm1 / y weights (shared dot block): 50 half2 pairs over k=0..99 (m-index)
    half2_t w1r[50];
#pragma unroll
    for (int c = 0; c < 50; ++c) {
        float a0 = 0.f, a1 = 0.f;
        if (hAct) {
            a0 = kap_s[2 * c]     * W1[(SDIM + 2 * c)     * HDIM + n];
            a1 = kap_s[2 * c + 1] * W1[(SDIM + 2 * c + 1) * HDIM + n];
        } else if (yAct) {
            a0 = Wy[(2 * c) * 10 + o];
            a1 = Wy[(2 * c + 1) * 10 + o];
        }
        w1r[c] = pk2(a0, a1);
    }
    float base_b = hAct ? b1[n] : (yAct ? by[o] : 0.f);

    // mm2 partial weights: wave w's k-range [50w, 50w+50), cols j0, j1
    const int j0 = 2 * lane, j1 = 2 * lane + 1;
    half2_t w2r[50];
#pragma unroll
    for (int c = 0; c < 25; ++c) {
        float a00 = 0.f, a10 = 0.f, a01 = 0.f, a11 = 0.f;
        if (hAct) {
            int k0 = 50 * w + 2 * c, k1 = k0 + 1;
            a00 = W2[k0 * MDIM + j0]; a10 = W2[k1 * MDIM + j0];
            a01 = W2[k0 * MDIM + j1]; a11 = W2[k1 * MDIM + j1];
        }
        w2r[2 * c]     = pk2(a00, a10);
        w2r[2 * c + 1] = pk2(a01, a11);
    }

    float kap0 = 0.f, kap1 = 0.f, cm0 = 0.f, cm1 = 0.f, b2k0 = 0.f, b2k1 = 0.f;
    if (hAct) {
        kap0 = kap_s[j0]; kap1 = kap_s[j1];
        cm0 = cm_s[j0];   cm1 = cm_s[j1];
        b2k0 = b2[j0] * KEXP;  b2k1 = b2[j1] * KEXP;
    }

    const unsigned short* Zb = Z + (size_t)b * TSTEPS * HDIM;
    float* outb = out + (size_t)b * TSTEPS * 10;

    float u = 0.f, m0 = 0.f, m1 = 0.f;
    unsigned short zA = 0, zB = 0;          // 2-step-ahead z prefetch
    if (hAct) { zA = Zb[n]; zB = Zb[HDIM + n]; }

    int sm[50];                             // m pairs broadcast (sgpr-resident)
#pragma unroll
    for (int c = 0; c < 50; ++c) sm[c] = 0;

    __syncthreads();

    auto stepf = [&](const int P, unsigned short& zreg, const int st) {
        // ---- unified dot block (4 chains): h (lanes<50) / y_{st-1} (w0 50-59)
        u = 0.81873075307798182f * u + bf2f(zreg);     // exp(-1/5); 0 on non-h lanes
        if (hAct) {
            int stn = st + 2; stn = (stn < TSTEPS) ? stn : TSTEPS - 1;
            zreg = Zb[(size_t)stn * HDIM + n];         // 2-step-ahead prefetch
        }
        float d0 = base_b + u, d1 = 0.f, d2 = 0.f, d3 = 0.f;
#pragma unroll
        for (int c = 0; c < 48; c += 4) {
            d0 = __builtin_amdgcn_fdot2(w1r[c+0], as_h2((unsigned)sm[c+0]), d0, false);
            d1 = __builtin_amdgcn_fdot2(w1r[c+1], as_h2((unsigned)sm[c+1]), d1, false);
            d2 = __builtin_amdgcn_fdot2(w1r[c+2], as_h2((unsigned)sm[c+2]), d2, false);
            d3 = __builtin_amdgcn_fdot2(w1r[c+3], as_h2((unsigned)sm[c+3]), d3, false);
        }
        d0 = __builtin_amdgcn_fdot2(w1r[48], as_h2((unsigned)sm[48]), d0, false);
        d1 = __builtin_amdgcn_fdot2(w1r[49], as_h2((unsigned)sm[49]), d1, false);
        float r = (d0 + d1) + (d2 + d3);
        if (yAct && st > 0) outb[(size_t)(st - 1) * 10 + o] = r;
        float h = fmaxf(r, 0.f);

        // ---- in-wave h broadcast: pack pairs, 25 readlanes
        float ho = __shfl_xor(h, 1);
        unsigned hpk = as_u32(pk2(h, ho));
        int sh[25];
#pragma unroll
        for (int c = 0; c < 25; ++c) sh[c] = __builtin_amdgcn_readlane((int)hpk, 2 * c);

        // ---- mm2 partial (4 chains): 2 cols over this wave's 50 h's
        if (hAct) {
            float a00 = 0.f, a01 = 0.f, a10 = 0.f, a11 = 0.f;
#pragma unroll
            for (int c = 0; c < 24; c += 2) {
                a00 = __builtin_amdgcn_fdot2(w2r[2*c],   as_h2((unsigned)sh[c]),   a00, false);
                a10 = __builtin_amdgcn_fdot2(w2r[2*c+1], as_h2((unsigned)sh[c]),   a10, false);
                a01 = __builtin_amdgcn_fdot2(w2r[2*c+2], as_h2((unsigned)sh[c+1]), a01, false);
                a11 = __builtin_amdgcn_fdot2(w2r[2*c+3], as_h2((unsigned)sh[c+1]), a11, false);
            }
            a00 = __builtin_amdgcn_fdot2(w2r[48], as_h2((unsigned)sh[24]), a00, false);
            a10 = __builtin_amdgcn_fdot2(w2r[49], as_h2((unsigned)sh[24]), a10, false);
            *(float2*)&part[P][w][j0] = make_float2(a00 + a01, a10 + a11);
        }
        wg_barrier();

        // ---- combine partials, tanh (exp2+rcp), m update (redundant all waves)
        if (hAct) {
            float2 q0 = *(const float2*)&part[P][0][j0];
            float2 q1 = *(const float2*)&part[P][1][j0];
            float2 q2 = *(const float2*)&part[P][2][j0];
            float2 q3 = *(const float2*)&part[P][3][j0];
            float s0 = (q0.x + q1.x) + (q2.x + q3.x);
            float s1 = (q0.y + q1.y) + (q2.y + q3.y);
            float e0 = __builtin_amdgcn_exp2f(fmaf(s0, KEXP, b2k0));  // e^{2x}
            float e1 = __builtin_amdgcn_exp2f(fmaf(s1, KEXP, b2k1));
            float dm0 = 1.7159f * (1.f - 2.f * __builtin_amdgcn_rcpf(e0 + 1.f));
            float dm1 = 1.7159f * (1.f - 2.f * __builtin_amdgcn_rcpf(e1 + 1.f));
            m0 = fmaf(kap0, m0, cm0 * dm0);            // m_t
            m1 = fmaf(kap1, m1, cm1 * dm1);
        }
        unsigned mpk = as_u32(pk2(m0, m1));
#pragma unroll
        for (int c = 0; c < 50; ++c) sm[c] = __builtin_amdgcn_readlane((int)mpk, c);
    };

#pragma unroll 1
    for (int st = 0; st < TSTEPS; st += 2) {
        stepf(0, zA, st);
        stepf(1, zB, st + 1);
    }

    // final y (step TSTEPS-1) from the last m broadcast
    if (yAct) {
        float d0 = base_b, d1 = 0.f, d2 = 0.f, d3 = 0.f;
#pragma unroll
        for (int c = 0; c < 48; c += 4) {
            d0 = __builtin_amdgcn_fdot2(w1r[c+0], as_h2((unsigned)sm[c+0]), d0, false);
            d1 = __builtin_amdgcn_fdot2(w1r[c+1], as_h2((unsigned)sm[c+1]), d1, false);
            d2 = __builtin_amdgcn_fdot2(w1r[c+2], as_h2((unsigned)sm[c+2]), d2, false);
            d3 = __builtin_amdgcn_fdot2(w1r[c+3], as_h2((unsigned)sm[c+3]), d3, false);
        }
        d0 = __builtin_amdgcn_fdot2(w1r[48], as_h2((unsigned)sm[48]), d0, false);
        d1 = __builtin_amdgcn_fdot2(w1r[49], as_h2((unsigned)sm[49]), d1, false);
        outb[(size_t)(TSTEPS - 1) * 10 + o] = (d0 + d1) + (d2 + d3);
    }
}

extern "C" void kernel_launch(void* const* d_in, const int* in_sizes, int n_in,
                              void* d_out, int out_size, void* d_ws, size_t ws_size,
                              hipStream_t stream) {
    const float* X  = (const float*)d_in[0];
    const float* ws = (const float*)d_in[1];
    const float* W1 = (const float*)d_in[2];
    const float* b1 = (const float*)d_in[3];
    const float* W2 = (const float*)d_in[4];
    const float* b2 = (const float*)d_in[5];
    const float* Wy = (const float*)d_in[6];
    const float* by = (const float*)d_in[7];
    float* out = (float*)d_out;

    unsigned short* wpt = (unsigned short*)d_ws;
    unsigned short* Z   = (unsigned short*)((char*)d_ws + Z_OFF);

    hipLaunchKernelGGL(prep_wpt, dim3((NPAD * KPAD) / 256), dim3(256), 0, stream, ws, W1, wpt);
    hipLaunchKernelGGL(gemm_z, dim3(MT / 128), dim3(256), 0, stream, X, wpt, Z);
    hipLaunchKernelGGL(scan_seq, dim3(BATCH), dim3(256), 0, stream,
                       Z, W1, b1, W2, b2, Wy, by, out);
}